// Round 9
// baseline (2654.580 us; speedup 1.0000x reference)
//
#include <hip/hip_runtime.h>

// ---------------------------------------------------------------------------
// SAGENET: x:(8192,16384)f32 -> lin1(16384->4096,relu) -> lin2(4096->2048,relu)
// -> SAGEConv(2048->1024,relu) -> SAGEConv(1024->10,relu) -> softmax
// R9: cross-block desync GEMM. Tile 128x256, 4 waves/block (256 thr),
//     per-wave 128x64 (acc[8][4], ~218 regs <= 256 cap at (256,2)), BK=32,
//     LDS 2x24 KiB = 48 KiB -> 2 independent blocks/CU. Same proven 2-barrier
//     loop (R5/R8) + R6's measured-0-conflict 64B-row swizzle + XCD mapping.
//     Mechanism: the 2 waves/SIMD now come from DIFFERENT blocks, so one
//     block's barrier drain is covered by the other's MFMAs (m114).
//     R7 lesson honored: 8-wave blocks can never fit 2/CU with acc[8][4].
// Workspace peak: ~505.2 MiB.
// ---------------------------------------------------------------------------

typedef short  short8   __attribute__((ext_vector_type(8)));
typedef float  floatx4  __attribute__((ext_vector_type(4)));
typedef unsigned short ushort8v __attribute__((ext_vector_type(8)));
typedef unsigned short ushort4v __attribute__((ext_vector_type(4)));
typedef unsigned short ushort;

__device__ __forceinline__ ushort f2bf(float f) {
  unsigned u = __float_as_uint(f);
  u += 0x7fffu + ((u >> 16) & 1u);   // round-to-nearest-even
  return (ushort)(u >> 16);
}
__device__ __forceinline__ float bf2f(ushort h) {
  return __uint_as_float(((unsigned)h) << 16);
}

__device__ __forceinline__ void gload16(const void* g, void* l) {
  __builtin_amdgcn_global_load_lds(
      (const __attribute__((address_space(1))) void*)g,
      (__attribute__((address_space(3))) void*)l, 16, 0, 0);
}

// ---------------- f32 -> bf16 conversion (vectorized, grid-stride) ----------
__global__ __launch_bounds__(256) void cvt_f32_bf16(
    const float* __restrict__ in, ushort* __restrict__ out, long n8) {
  long i = (long)blockIdx.x * blockDim.x + threadIdx.x;
  const long stride = (long)gridDim.x * blockDim.x;
  for (; i < n8; i += stride) {
    const float4* p = (const float4*)(in + i * 8);
    float4 a = p[0], b = p[1];
    ushort8v o;
    o[0] = f2bf(a.x); o[1] = f2bf(a.y); o[2] = f2bf(a.z); o[3] = f2bf(a.w);
    o[4] = f2bf(b.x); o[5] = f2bf(b.y); o[6] = f2bf(b.z); o[7] = f2bf(b.w);
    *(ushort8v*)(out + i * 8) = o;
  }
}

// ---------------- CSR build -------------------------------------------------
__global__ void edge_count(const int* __restrict__ dst, int E, int* __restrict__ deg) {
  int e = blockIdx.x * 256 + threadIdx.x;
  if (e < E) atomicAdd(&deg[dst[e]], 1);
}

__global__ __launch_bounds__(256) void scan_k(
    const int* __restrict__ deg, int* __restrict__ offs, float* __restrict__ inv, int n) {
  __shared__ int part[256];
  const int t = threadIdx.x;
  int local[32];
  int s = 0;
  const int base = t * 32;
#pragma unroll
  for (int i = 0; i < 32; ++i) { local[i] = s; s += deg[base + i]; }
  part[t] = s;
  __syncthreads();
  for (int off = 1; off < 256; off <<= 1) {
    int v = (t >= off) ? part[t - off] : 0;
    __syncthreads();
    part[t] += v;
    __syncthreads();
  }
  const int prev = (t == 0) ? 0 : part[t - 1];
  if (t == 255) offs[n] = part[255];
#pragma unroll
  for (int i = 0; i < 32; ++i) {
    const int e = base + i;
    offs[e] = prev + local[i];
    const int d = deg[e];
    inv[e] = (d > 0) ? (1.0f / (float)d) : 0.0f;
  }
}

__global__ void edge_fill(const int* __restrict__ src, const int* __restrict__ dst, int E,
                          const int* __restrict__ offs, int* __restrict__ fill,
                          int* __restrict__ csr) {
  int e = blockIdx.x * 256 + threadIdx.x;
  if (e < E) {
    const int d = dst[e];
    const int p = offs[d] + atomicAdd(&fill[d], 1);
    csr[p] = src[e];
  }
}

// ---------------- bf16 GEMM 128x256, C = A * B^T, 2 blocks/CU ---------------
// A: [M,K] bf16 row-major; B: [N,K] bf16 row-major. BK=32, 4 waves (1Mx4N),
// per-wave 128x64 output (acc[8][4]). LDS 2 bufs x 24 KiB (A 8K | B 16K).
// Row = 64 B (BK=32). Logical 16B-chunk c of row r at physical chunk
// c ^ ((r>>1)&3)  (R6-measured: 0 bank conflicts). global_load_lds dest
// linear; SOURCE chunk pre-permuted by the same involution.
// Block mapping: XCD x (= blockIdx%8) owns bm panels [x*nbm/8,(x+1)*nbm/8),
// bn-inner sweep.
template <int OUT_BF16, int RELU, int HAS_BIAS>
__global__ __launch_bounds__(256, 2) void gemm128(
    const ushort* __restrict__ A, const ushort* __restrict__ Bm,
    const float* __restrict__ bias, void* __restrict__ Cout,
    int M, int N, int K) {
  extern __shared__ char smem[];   // 2 x 24576

  const int nbn = N >> 8;
  const int nbm8 = (M >> 7) >> 3;        // bm panels per XCD
  const int x = blockIdx.x & 7;          // XCD id under round-robin dispatch
  const int j = blockIdx.x >> 3;
  const int bm = x * nbm8 + j / nbn;
  const int bn = j % nbn;

  const int t = threadIdx.x;
  const int wc = t >> 6, lane = t & 63;
  const int lr = lane & 15;

  // ---- staging source (pre-swizzled): thread t -> LDS byte t*16 of a 4 KiB
  //      region slice = row t>>2, phys chunk t&3; logical q = (t&3)^((t>>3)&3)
  const int q = (t & 3) ^ ((t >> 3) & 3);
  const ushort* Ag = A  + (size_t)(bm * 128 + (t >> 2)) * K + q * 8;
  const ushort* Bg = Bm + (size_t)(bn * 256 + (t >> 2)) * K + q * 8;
  const size_t rsk = (size_t)64 * K;
  const int st_ = t * 16;

  // ---- fragment read offsets (swizzled; row = 16*frag + lr) ----
  const int frOff = (((lane >> 4) ^ ((lr >> 1) & 3)) << 4);
  const int rdA = lr * 64 + frOff;                    // + mi*1024
  const int rdB = (wc * 64 + lr) * 64 + frOff + 8192; // + ni*1024

  floatx4 acc[8][4] = {};
  const int NT = K >> 5;

#define STAGE(tile)                                                   \
  {                                                                   \
    const int k0_ = (tile) << 5;                                      \
    char* b_ = smem + ((tile) & 1) * 24576 + st_;                     \
    gload16(Ag + k0_, b_);                                            \
    gload16(Ag + rsk + k0_, b_ + 4096);                               \
    gload16(Bg + k0_, b_ + 8192);                                     \
    gload16(Bg + rsk + k0_, b_ + 12288);                              \
    gload16(Bg + 2 * rsk + k0_, b_ + 16384);                          \
    gload16(Bg + 3 * rsk + k0_, b_ + 20480);                          \
  }

  STAGE(0);
  __syncthreads();   // tile 0 staged

  for (int kt = 0; kt < NT; ++kt) {
    const char* pa = smem + (kt & 1) * 24576 + rdA;
    const char* pb = smem + (kt & 1) * 24576 + rdB;
    short8 af[8], bfv[4];
#pragma unroll
    for (int mi = 0; mi < 8; ++mi) af[mi] = *(const short8*)(pa + mi * 1024);
#pragma unroll
    for (int ni = 0; ni < 4; ++ni) bfv[ni] = *(const short8*)(pb + ni * 1024);

    if (kt + 1 < NT) STAGE(kt + 1);   // prefetch into other buffer

#pragma unroll
    for (int mi = 0; mi < 8; ++mi)
#pragma unroll
      for (int ni = 0; ni < 4; ++ni)
        acc[mi][ni] = __builtin_amdgcn_mfma_f32_16x16x32_bf16(af[mi], bfv[ni], acc[mi][ni], 0, 0, 0);

    __syncthreads();   // drains staging; next buffer ready
  }

#undef STAGE

  // epilogue: C/D layout col=lane&15, row=(lane>>4)*4+j (m89-verified)
  const int row0 = bm * 128 + ((lane >> 4) << 2);
  const int col0 = bn * 256 + wc * 64 + lr;
#pragma unroll
  for (int ni = 0; ni < 4; ++ni) {
    const int col = col0 + ni * 16;
    const float bv = HAS_BIAS ? bias[col] : 0.0f;
#pragma unroll
    for (int mi = 0; mi < 8; ++mi) {
#pragma unroll
      for (int j2 = 0; j2 < 4; ++j2) {
        const int row = row0 + mi * 16 + j2;
        float v = acc[mi][ni][j2] + bv;
        if (RELU) v = fmaxf(v, 0.0f);
        if (OUT_BF16)
          ((ushort*)Cout)[(size_t)row * N + col] = f2bf(v);
        else
          ((float*)Cout)[(size_t)row * N + col] = v;
      }
    }
  }
}

// ---------------- SAGE1 aggregation + combine (bf16 hlr1) -------------------
__global__ __launch_bounds__(256) void sage1_agg(
    const ushort* __restrict__ hlr1, const int* __restrict__ offs,
    const int* __restrict__ csr, const float* __restrict__ inv,
    const float* __restrict__ lb, ushort* __restrict__ h3) {
  const int dn = blockIdx.x;
  const int f4 = threadIdx.x * 4;
  float ax = 0.f, ay = 0.f, az = 0.f, aw = 0.f;
  const int e0 = offs[dn], e1 = offs[dn + 1];
  for (int e = e0; e < e1; ++e) {
    const int s = csr[e];
    const ushort4v v = *(const ushort4v*)(hlr1 + (size_t)s * 2048 + f4);
    ax += bf2f(v[0]); ay += bf2f(v[1]); az += bf2f(v[2]); aw += bf2f(v[3]);
  }
  const float iv = inv[dn];
  const ushort4v hr = *(const ushort4v*)(hlr1 + (size_t)dn * 2048 + 1024 + f4);
  const float4 bb = *(const float4*)(lb + f4);
  ushort4v o;
  o[0] = f2bf(fmaxf(ax * iv + bb.x + bf2f(hr[0]), 0.0f));
  o[1] = f2bf(fmaxf(ay * iv + bb.y + bf2f(hr[1]), 0.0f));
  o[2] = f2bf(fmaxf(az * iv + bb.z + bf2f(hr[2]), 0.0f));
  o[3] = f2bf(fmaxf(aw * iv + bb.w + bf2f(hr[3]), 0.0f));
  *(ushort4v*)(h3 + (size_t)dn * 1024 + f4) = o;
}

// ---------------- SAGE2 projections (K=1024, N=10 each) ---------------------
__global__ __launch_bounds__(64) void sage2_mm(
    const ushort* __restrict__ h3, const float* __restrict__ wl,
    const float* __restrict__ wr, float* __restrict__ hl2, float* __restrict__ hr2) {
  const int row = blockIdx.x;
  const int l = threadIdx.x;
  float hv[16];
  {
    ushort8v p0 = *(const ushort8v*)(h3 + (size_t)row * 1024 + l * 16);
    ushort8v p1 = *(const ushort8v*)(h3 + (size_t)row * 1024 + l * 16 + 8);
#pragma unroll
    for (int i = 0; i < 8; ++i) { hv[i] = bf2f(p0[i]); hv[8 + i] = bf2f(p1[i]); }
  }
  float al[10] = {}, ar[10] = {};
#pragma unroll
  for (int i = 0; i < 16; ++i) {
    const int k = l * 16 + i;
    const float h = hv[i];
#pragma unroll
    for (int j = 0; j < 10; ++j) {
      al[j] = fmaf(h, wl[j * 1024 + k], al[j]);
      ar[j] = fmaf(h, wr[j * 1024 + k], ar[j]);
    }
  }
#pragma unroll
  for (int j = 0; j < 10; ++j) {
#pragma unroll
    for (int off = 32; off > 0; off >>= 1) {
      al[j] += __shfl_down(al[j], off);
      ar[j] += __shfl_down(ar[j], off);
    }
  }
  if (l == 0) {
#pragma unroll
    for (int j = 0; j < 10; ++j) {
      hl2[(size_t)row * 10 + j] = al[j];
      hr2[(size_t)row * 10 + j] = ar[j];
    }
  }
}

// ---------------- SAGE2 aggregation + combine + softmax ---------------------
__global__ __launch_bounds__(64) void sage2_final(
    const float* __restrict__ hl2, const float* __restrict__ hr2,
    const int* __restrict__ offs, const int* __restrict__ csr,
    const float* __restrict__ inv, const float* __restrict__ lb,
    float* __restrict__ out) {
  const int dn = blockIdx.x;
  const int l = threadIdx.x;
  float a[10] = {};
  const int e0 = offs[dn], e1 = offs[dn + 1];
  for (int e = e0 + l; e < e1; e += 64) {
    const int s = csr[e];
#pragma unroll
    for (int j = 0; j < 10; ++j) a[j] += hl2[(size_t)s * 10 + j];
  }
#pragma unroll
  for (int j = 0; j < 10; ++j)
#pragma unroll
    for (int off = 32; off > 0; off >>= 1) a[j] += __shfl_down(a[j], off);
  if (l == 0) {
    const float iv = inv[dn];
    float v[10];
    float m = -1e30f;
#pragma unroll
    for (int j = 0; j < 10; ++j) {
      v[j] = fmaxf(a[j] * iv + lb[j] + hr2[(size_t)dn * 10 + j], 0.0f);
      m = fmaxf(m, v[j]);
    }
    float ssum = 0.0f;
#pragma unroll
    for (int j = 0; j < 10; ++j) { v[j] = __expf(v[j] - m); ssum += v[j]; }
    const float r = 1.0f / ssum;
#pragma unroll
    for (int j = 0; j < 10; ++j) out[(size_t)dn * 10 + j] = v[j] * r;
  }
}

// ---------------------------------------------------------------------------
extern "C" void kernel_launch(void* const* d_in, const int* in_sizes, int n_in,
                              void* d_out, int out_size, void* d_ws, size_t ws_size,
                              hipStream_t stream) {
  const float* x    = (const float*)d_in[0];
  const int*   ei   = (const int*)d_in[1];
  const float* w1   = (const float*)d_in[2];
  const float* b1   = (const float*)d_in[3];
  const float* w2   = (const float*)d_in[4];
  const float* b2   = (const float*)d_in[5];
  const float* s1lw = (const float*)d_in[6];
  const float* s1lb = (const float*)d_in[7];
  const float* s1rw = (const float*)d_in[8];
  const float* s2lw = (const float*)d_in[9];
  const float* s2lb = (const float*)d_in[10];
  const float* s2rw = (const float*)d_in[11];
  float* out = (float*)d_out;
  char* ws = (char*)d_ws;

  const int E = in_sizes[1] / 2;  // 262144
  const int Nn = 8192;

  // allow 48 KiB dynamic LDS for the GEMM instantiations (idempotent)
  hipFuncSetAttribute((const void*)&gemm128<1, 1, 1>,
                      hipFuncAttributeMaxDynamicSharedMemorySize, 49152);
  hipFuncSetAttribute((const void*)&gemm128<1, 0, 0>,
                      hipFuncAttributeMaxDynamicSharedMemorySize, 49152);

  // ---- workspace layout (bytes) ----
  ushort* xb  = (ushort*)(ws + 0L);           // 256 MiB
  ushort* w1b = (ushort*)(ws + 268435456L);   // 128 MiB
  ushort* h1  = (ushort*)(ws + 402653184L);   //  64 MiB
  ushort* w2b = (ushort*)(ws + 469762048L);   //  16 MiB
  ushort* h2  = (ushort*)(ws + 486539264L);   //  32 MiB
  ushort* ws1 = (ushort*)(ws + 520093696L);   //   8 MiB  [s1_l_w ; s1_r_w]
  char* csrb = ws + 528482304L;
  int*   deg  = (int*)(csrb);
  int*   fill = (int*)(csrb + 32768);
  int*   offs = (int*)(csrb + 65536);
  float* inv  = (float*)(csrb + 98816);
  int*   csr  = (int*)(csrb + 131584);
  // region reuse (xb dead after GEMM1, h1 dead after GEMM2):
  ushort* hlr1 = (ushort*)(ws + 0L);                // 32 MiB bf16 [hl1 | hr1]
  ushort* h3   = (ushort*)(ws + 67108864L);         // 16 MiB
  float*  hl2  = (float*)(ws + 83886080L);
  float*  hr2  = (float*)(ws + 84213760L);

  const int* esrc = ei;
  const int* edst = ei + E;

  hipMemsetAsync(deg, 0, 65536, stream);  // deg + fill counters

  // bf16 conversions
  cvt_f32_bf16<<<4096, 256, 0, stream>>>(x, xb, 16777216L);
  cvt_f32_bf16<<<2048, 256, 0, stream>>>(w1, w1b, 8388608L);
  cvt_f32_bf16<<<1024, 256, 0, stream>>>(w2, w2b, 1048576L);
  cvt_f32_bf16<<<256, 256, 0, stream>>>(s1lw, ws1, 262144L);
  cvt_f32_bf16<<<256, 256, 0, stream>>>(s1rw, ws1 + 2097152L, 262144L);

  // CSR build
  edge_count<<<(E + 255) / 256, 256, 0, stream>>>(edst, E, deg);
  scan_k<<<1, 256, 0, stream>>>(deg, offs, inv, Nn);
  edge_fill<<<(E + 255) / 256, 256, 0, stream>>>(esrc, edst, E, offs, fill, csr);

  // MLP (128x256-tile GEMMs, 48 KiB dynamic LDS, 2 blocks/CU)
  gemm128<1, 1, 1><<<1024, 256, 49152, stream>>>(xb, w1b, b1, h1, 8192, 4096, 16384);
  gemm128<1, 1, 1><<<512, 256, 49152, stream>>>(h1, w2b, b2, h2, 8192, 2048, 4096);
  // fused SAGE1 projections: [hl1 | hr1] = h2 @ [s1_l_w ; s1_r_w]^T  (bf16 out)
  gemm128<1, 0, 0><<<512, 256, 49152, stream>>>(h2, ws1, nullptr, hlr1, 8192, 2048, 2048);

  sage1_agg<<<8192, 256, 0, stream>>>(hlr1, offs, csr, inv, s1lb, h3);
  sage2_mm<<<8192, 64, 0, stream>>>(h3, s2lw, s2rw, hl2, hr2);
  sage2_final<<<8192, 64, 0, stream>>>(hl2, hr2, offs, csr, inv, s2lb, out);
}

// Round 10
// 1987.407 us; speedup vs baseline: 1.3357x; 1.3357x over previous
//
#include <hip/hip_runtime.h>

// ---------------------------------------------------------------------------
// SAGENET: x:(8192,16384)f32 -> lin1(16384->4096,relu) -> lin2(4096->2048,relu)
// -> SAGEConv(2048->1024,relu) -> SAGEConv(1024->10,relu) -> softmax
// R10: 256x256 GEMM, BK=32, TRIPLE-buffered LDS (3x32 KiB = 96 KiB), depth-2
//      prefetch + counted s_waitcnt vmcnt(4) at the single per-K-tile barrier
//      (T4: loads span the barrier; tile kt+1 had a full iteration to land).
//      Keeps: 64B-row swizzle measured 0-conflict (R6/R9), XCD-partitioned
//      mapping, acc[8][4] per wave, same K-accumulation order as R5/R8
//      (absmax canary 0.002929688). Tail stages clamp to K=0 into buffers
//      never read (uniform wait count).
//      R7 lesson: launch_bounds stays (512,2); R9 lesson: tile stays 256x256.
// Workspace peak: ~505.2 MiB.
// ---------------------------------------------------------------------------

typedef short  short8   __attribute__((ext_vector_type(8)));
typedef float  floatx4  __attribute__((ext_vector_type(4)));
typedef unsigned short ushort8v __attribute__((ext_vector_type(8)));
typedef unsigned short ushort4v __attribute__((ext_vector_type(4)));
typedef unsigned short ushort;

__device__ __forceinline__ ushort f2bf(float f) {
  unsigned u = __float_as_uint(f);
  u += 0x7fffu + ((u >> 16) & 1u);   // round-to-nearest-even
  return (ushort)(u >> 16);
}
__device__ __forceinline__ float bf2f(ushort h) {
  return __uint_as_float(((unsigned)h) << 16);
}

__device__ __forceinline__ void gload16(const void* g, void* l) {
  __builtin_amdgcn_global_load_lds(
      (const __attribute__((address_space(1))) void*)g,
      (__attribute__((address_space(3))) void*)l, 16, 0, 0);
}

// ---------------- f32 -> bf16 conversion (vectorized, grid-stride) ----------
__global__ __launch_bounds__(256) void cvt_f32_bf16(
    const float* __restrict__ in, ushort* __restrict__ out, long n8) {
  long i = (long)blockIdx.x * blockDim.x + threadIdx.x;
  const long stride = (long)gridDim.x * blockDim.x;
  for (; i < n8; i += stride) {
    const float4* p = (const float4*)(in + i * 8);
    float4 a = p[0], b = p[1];
    ushort8v o;
    o[0] = f2bf(a.x); o[1] = f2bf(a.y); o[2] = f2bf(a.z); o[3] = f2bf(a.w);
    o[4] = f2bf(b.x); o[5] = f2bf(b.y); o[6] = f2bf(b.z); o[7] = f2bf(b.w);
    *(ushort8v*)(out + i * 8) = o;
  }
}

// ---------------- CSR build -------------------------------------------------
__global__ void edge_count(const int* __restrict__ dst, int E, int* __restrict__ deg) {
  int e = blockIdx.x * 256 + threadIdx.x;
  if (e < E) atomicAdd(&deg[dst[e]], 1);
}

__global__ __launch_bounds__(256) void scan_k(
    const int* __restrict__ deg, int* __restrict__ offs, float* __restrict__ inv, int n) {
  __shared__ int part[256];
  const int t = threadIdx.x;
  int local[32];
  int s = 0;
  const int base = t * 32;
#pragma unroll
  for (int i = 0; i < 32; ++i) { local[i] = s; s += deg[base + i]; }
  part[t] = s;
  __syncthreads();
  for (int off = 1; off < 256; off <<= 1) {
    int v = (t >= off) ? part[t - off] : 0;
    __syncthreads();
    part[t] += v;
    __syncthreads();
  }
  const int prev = (t == 0) ? 0 : part[t - 1];
  if (t == 255) offs[n] = part[255];
#pragma unroll
  for (int i = 0; i < 32; ++i) {
    const int e = base + i;
    offs[e] = prev + local[i];
    const int d = deg[e];
    inv[e] = (d > 0) ? (1.0f / (float)d) : 0.0f;
  }
}

__global__ void edge_fill(const int* __restrict__ src, const int* __restrict__ dst, int E,
                          const int* __restrict__ offs, int* __restrict__ fill,
                          int* __restrict__ csr) {
  int e = blockIdx.x * 256 + threadIdx.x;
  if (e < E) {
    const int d = dst[e];
    const int p = offs[d] + atomicAdd(&fill[d], 1);
    csr[p] = src[e];
  }
}

// ---------------- bf16 GEMM 256x256, BK=32, 3-buffer counted pipeline -------
// A: [M,K] bf16 row-major; B: [N,K] bf16 row-major. 8 waves (2Mx4N),
// per-wave 128x64 output (acc[8][4]). LDS 3 bufs x 32 KiB (A 16K | B 16K).
// Row = 64 B. Logical 16B-chunk c of row r at physical chunk c ^ ((r>>1)&3)
// (R6/R9-measured: 0 bank conflicts). gload_lds dest linear; SOURCE chunk
// pre-permuted by the same involution.
// Pipeline: stage tiles 0,1; iter kt: read buf[kt%3], stage kt+2 (clamped)
// into buf[(kt+2)%3], 32 MFMA, s_waitcnt vmcnt(4) (kt+1 landed, kt+2 in
// flight), s_barrier. WAR-safe: buf[(kt+2)%3]'s readers finished in iter
// kt-1, before the barrier that precedes this stage.
template <int OUT_BF16, int RELU, int HAS_BIAS>
__global__ __launch_bounds__(512, 2) void gemm256(
    const ushort* __restrict__ A, const ushort* __restrict__ Bm,
    const float* __restrict__ bias, void* __restrict__ Cout,
    int M, int N, int K) {
  extern __shared__ char smem[];   // 3 x 32768

  const int nbn = N >> 8;
  const int nbm8 = (M >> 8) >> 3;        // bm panels per XCD
  const int x = blockIdx.x & 7;          // XCD id under round-robin dispatch
  const int j = blockIdx.x >> 3;
  const int bm = x * nbm8 + j / nbn;
  const int bn = j % nbn;

  const int t = threadIdx.x;
  const int w = t >> 6, lane = t & 63;
  const int wr = w >> 2, wc = w & 3;
  const int lr = lane & 15;

  // ---- staging source (pre-swizzled): thread t -> LDS bytes t*16 linear;
  //      region row = t>>2, phys chunk = t&3; logical q = (t&3)^((t>>3)&3) ----
  const int q = (t & 3) ^ ((t >> 3) & 3);
  const ushort* Ag = A  + (size_t)(bm * 256 + (t >> 2)) * K + q * 8;
  const ushort* Bg = Bm + (size_t)(bn * 256 + (t >> 2)) * K + q * 8;
  const size_t rsk = (size_t)128 * K;   // +128 rows
  const int st_ = t * 16;

  // ---- fragment read offsets (swizzled) ----
  const int frOff = (((lane >> 4) ^ ((lr >> 1) & 3)) << 4);
  const int rdA = (wr * 128 + lr) * 64 + frOff;           // + mi*1024
  const int rdB = (wc * 64 + lr) * 64 + 16384 + frOff;    // + ni*1024

  floatx4 acc[8][4] = {};
  const int NT = K >> 5;

#define STAGE(tile, buf)                                              \
  {                                                                   \
    const int kk_ = ((tile) < NT ? (tile) : 0) << 5;                  \
    char* b_ = smem + (buf) * 32768 + st_;                            \
    gload16(Ag + kk_, b_);                                            \
    gload16(Ag + rsk + kk_, b_ + 8192);                               \
    gload16(Bg + kk_, b_ + 16384);                                    \
    gload16(Bg + rsk + kk_, b_ + 24576);                              \
  }

  // prologue: stage tiles 0 and 1 (8 loads); wait for tile 0 (leave 4)
  STAGE(0, 0);
  STAGE(1, 1);
  asm volatile("s_waitcnt vmcnt(4)" ::: "memory");
  __builtin_amdgcn_s_barrier();
  asm volatile("" ::: "memory");

  int cur = 0, nxt2 = 2;   // kt%3 and (kt+2)%3
  for (int kt = 0; kt < NT; ++kt) {
    const char* pa = smem + cur * 32768 + rdA;
    const char* pb = smem + cur * 32768 + rdB;
    short8 af[8], bfv[4];
#pragma unroll
    for (int mi = 0; mi < 8; ++mi) af[mi] = *(const short8*)(pa + mi * 1024);
#pragma unroll
    for (int ni = 0; ni < 4; ++ni) bfv[ni] = *(const short8*)(pb + ni * 1024);

    STAGE(kt + 2, nxt2);   // depth-2 prefetch (clamped at tail, buffer unread)

    __builtin_amdgcn_s_setprio(1);
#pragma unroll
    for (int mi = 0; mi < 8; ++mi)
#pragma unroll
      for (int ni = 0; ni < 4; ++ni)
        acc[mi][ni] = __builtin_amdgcn_mfma_f32_16x16x32_bf16(af[mi], bfv[ni], acc[mi][ni], 0, 0, 0);
    __builtin_amdgcn_s_setprio(0);

    // counted wait: tile kt+1's 4 loads landed; tile kt+2's stay in flight
    asm volatile("s_waitcnt vmcnt(4)" ::: "memory");
    __builtin_amdgcn_s_barrier();
    asm volatile("" ::: "memory");

    cur = (cur == 2) ? 0 : cur + 1;
    nxt2 = (nxt2 == 2) ? 0 : nxt2 + 1;
  }

#undef STAGE

  // epilogue: C/D layout col=lane&15, row=(lane>>4)*4+j (m89-verified)
  const int row0 = bm * 256 + wr * 128 + ((lane >> 4) << 2);
  const int col0 = bn * 256 + wc * 64 + lr;
#pragma unroll
  for (int ni = 0; ni < 4; ++ni) {
    const int col = col0 + ni * 16;
    const float bv = HAS_BIAS ? bias[col] : 0.0f;
#pragma unroll
    for (int mi = 0; mi < 8; ++mi) {
#pragma unroll
      for (int j2 = 0; j2 < 4; ++j2) {
        const int row = row0 + mi * 16 + j2;
        float v = acc[mi][ni][j2] + bv;
        if (RELU) v = fmaxf(v, 0.0f);
        if (OUT_BF16)
          ((ushort*)Cout)[(size_t)row * N + col] = f2bf(v);
        else
          ((float*)Cout)[(size_t)row * N + col] = v;
      }
    }
  }
}

// ---------------- SAGE1 aggregation + combine (bf16 hlr1) -------------------
__global__ __launch_bounds__(256) void sage1_agg(
    const ushort* __restrict__ hlr1, const int* __restrict__ offs,
    const int* __restrict__ csr, const float* __restrict__ inv,
    const float* __restrict__ lb, ushort* __restrict__ h3) {
  const int dn = blockIdx.x;
  const int f4 = threadIdx.x * 4;
  float ax = 0.f, ay = 0.f, az = 0.f, aw = 0.f;
  const int e0 = offs[dn], e1 = offs[dn + 1];
  for (int e = e0; e < e1; ++e) {
    const int s = csr[e];
    const ushort4v v = *(const ushort4v*)(hlr1 + (size_t)s * 2048 + f4);
    ax += bf2f(v[0]); ay += bf2f(v[1]); az += bf2f(v[2]); aw += bf2f(v[3]);
  }
  const float iv = inv[dn];
  const ushort4v hr = *(const ushort4v*)(hlr1 + (size_t)dn * 2048 + 1024 + f4);
  const float4 bb = *(const float4*)(lb + f4);
  ushort4v o;
  o[0] = f2bf(fmaxf(ax * iv + bb.x + bf2f(hr[0]), 0.0f));
  o[1] = f2bf(fmaxf(ay * iv + bb.y + bf2f(hr[1]), 0.0f));
  o[2] = f2bf(fmaxf(az * iv + bb.z + bf2f(hr[2]), 0.0f));
  o[3] = f2bf(fmaxf(aw * iv + bb.w + bf2f(hr[3]), 0.0f));
  *(ushort4v*)(h3 + (size_t)dn * 1024 + f4) = o;
}

// ---------------- SAGE2 projections (K=1024, N=10 each) ---------------------
__global__ __launch_bounds__(64) void sage2_mm(
    const ushort* __restrict__ h3, const float* __restrict__ wl,
    const float* __restrict__ wr, float* __restrict__ hl2, float* __restrict__ hr2) {
  const int row = blockIdx.x;
  const int l = threadIdx.x;
  float hv[16];
  {
    ushort8v p0 = *(const ushort8v*)(h3 + (size_t)row * 1024 + l * 16);
    ushort8v p1 = *(const ushort8v*)(h3 + (size_t)row * 1024 + l * 16 + 8);
#pragma unroll
    for (int i = 0; i < 8; ++i) { hv[i] = bf2f(p0[i]); hv[8 + i] = bf2f(p1[i]); }
  }
  float al[10] = {}, ar[10] = {};
#pragma unroll
  for (int i = 0; i < 16; ++i) {
    const int k = l * 16 + i;
    const float h = hv[i];
#pragma unroll
    for (int j = 0; j < 10; ++j) {
      al[j] = fmaf(h, wl[j * 1024 + k], al[j]);
      ar[j] = fmaf(h, wr[j * 1024 + k], ar[j]);
    }
  }
#pragma unroll
  for (int j = 0; j < 10; ++j) {
#pragma unroll
    for (int off = 32; off > 0; off >>= 1) {
      al[j] += __shfl_down(al[j], off);
      ar[j] += __shfl_down(ar[j], off);
    }
  }
  if (l == 0) {
#pragma unroll
    for (int j = 0; j < 10; ++j) {
      hl2[(size_t)row * 10 + j] = al[j];
      hr2[(size_t)row * 10 + j] = ar[j];
    }
  }
}

// ---------------- SAGE2 aggregation + combine + softmax ---------------------
__global__ __launch_bounds__(64) void sage2_final(
    const float* __restrict__ hl2, const float* __restrict__ hr2,
    const int* __restrict__ offs, const int* __restrict__ csr,
    const float* __restrict__ inv, const float* __restrict__ lb,
    float* __restrict__ out) {
  const int dn = blockIdx.x;
  const int l = threadIdx.x;
  float a[10] = {};
  const int e0 = offs[dn], e1 = offs[dn + 1];
  for (int e = e0 + l; e < e1; e += 64) {
    const int s = csr[e];
#pragma unroll
    for (int j = 0; j < 10; ++j) a[j] += hl2[(size_t)s * 10 + j];
  }
#pragma unroll
  for (int j = 0; j < 10; ++j)
#pragma unroll
    for (int off = 32; off > 0; off >>= 1) a[j] += __shfl_down(a[j], off);
  if (l == 0) {
    const float iv = inv[dn];
    float v[10];
    float m = -1e30f;
#pragma unroll
    for (int j = 0; j < 10; ++j) {
      v[j] = fmaxf(a[j] * iv + lb[j] + hr2[(size_t)dn * 10 + j], 0.0f);
      m = fmaxf(m, v[j]);
    }
    float ssum = 0.0f;
#pragma unroll
    for (int j = 0; j < 10; ++j) { v[j] = __expf(v[j] - m); ssum += v[j]; }
    const float r = 1.0f / ssum;
#pragma unroll
    for (int j = 0; j < 10; ++j) out[(size_t)dn * 10 + j] = v[j] * r;
  }
}

// ---------------------------------------------------------------------------
extern "C" void kernel_launch(void* const* d_in, const int* in_sizes, int n_in,
                              void* d_out, int out_size, void* d_ws, size_t ws_size,
                              hipStream_t stream) {
  const float* x    = (const float*)d_in[0];
  const int*   ei   = (const int*)d_in[1];
  const float* w1   = (const float*)d_in[2];
  const float* b1   = (const float*)d_in[3];
  const float* w2   = (const float*)d_in[4];
  const float* b2   = (const float*)d_in[5];
  const float* s1lw = (const float*)d_in[6];
  const float* s1lb = (const float*)d_in[7];
  const float* s1rw = (const float*)d_in[8];
  const float* s2lw = (const float*)d_in[9];
  const float* s2lb = (const float*)d_in[10];
  const float* s2rw = (const float*)d_in[11];
  float* out = (float*)d_out;
  char* ws = (char*)d_ws;

  const int E = in_sizes[1] / 2;  // 262144
  const int Nn = 8192;

  // allow 96 KiB dynamic LDS for the GEMM instantiations (idempotent)
  hipFuncSetAttribute((const void*)&gemm256<1, 1, 1>,
                      hipFuncAttributeMaxDynamicSharedMemorySize, 98304);
  hipFuncSetAttribute((const void*)&gemm256<1, 0, 0>,
                      hipFuncAttributeMaxDynamicSharedMemorySize, 98304);

  // ---- workspace layout (bytes) ----
  ushort* xb  = (ushort*)(ws + 0L);           // 256 MiB
  ushort* w1b = (ushort*)(ws + 268435456L);   // 128 MiB
  ushort* h1  = (ushort*)(ws + 402653184L);   //  64 MiB
  ushort* w2b = (ushort*)(ws + 469762048L);   //  16 MiB
  ushort* h2  = (ushort*)(ws + 486539264L);   //  32 MiB
  ushort* ws1 = (ushort*)(ws + 520093696L);   //   8 MiB  [s1_l_w ; s1_r_w]
  char* csrb = ws + 528482304L;
  int*   deg  = (int*)(csrb);
  int*   fill = (int*)(csrb + 32768);
  int*   offs = (int*)(csrb + 65536);
  float* inv  = (float*)(csrb + 98816);
  int*   csr  = (int*)(csrb + 131584);
  // region reuse (xb dead after GEMM1, h1 dead after GEMM2):
  ushort* hlr1 = (ushort*)(ws + 0L);                // 32 MiB bf16 [hl1 | hr1]
  ushort* h3   = (ushort*)(ws + 67108864L);         // 16 MiB
  float*  hl2  = (float*)(ws + 83886080L);
  float*  hr2  = (float*)(ws + 84213760L);

  const int* esrc = ei;
  const int* edst = ei + E;

  hipMemsetAsync(deg, 0, 65536, stream);  // deg + fill counters

  // bf16 conversions
  cvt_f32_bf16<<<4096, 256, 0, stream>>>(x, xb, 16777216L);
  cvt_f32_bf16<<<2048, 256, 0, stream>>>(w1, w1b, 8388608L);
  cvt_f32_bf16<<<1024, 256, 0, stream>>>(w2, w2b, 1048576L);
  cvt_f32_bf16<<<256, 256, 0, stream>>>(s1lw, ws1, 262144L);
  cvt_f32_bf16<<<256, 256, 0, stream>>>(s1rw, ws1 + 2097152L, 262144L);

  // CSR build
  edge_count<<<(E + 255) / 256, 256, 0, stream>>>(edst, E, deg);
  scan_k<<<1, 256, 0, stream>>>(deg, offs, inv, Nn);
  edge_fill<<<(E + 255) / 256, 256, 0, stream>>>(esrc, edst, E, offs, fill, csr);

  // MLP (256x256-tile GEMMs, 96 KiB dynamic LDS, counted-vmcnt pipeline)
  gemm256<1, 1, 1><<<512, 512, 98304, stream>>>(xb, w1b, b1, h1, 8192, 4096, 16384);
  gemm256<1, 1, 1><<<256, 512, 98304, stream>>>(h1, w2b, b2, h2, 8192, 2048, 4096);
  // fused SAGE1 projections: [hl1 | hr1] = h2 @ [s1_l_w ; s1_r_w]^T  (bf16 out)
  gemm256<1, 0, 0><<<256, 512, 98304, stream>>>(h2, ws1, nullptr, hlr1, 8192, 2048, 2048);

  sage1_agg<<<8192, 256, 0, stream>>>(hlr1, offs, csr, inv, s1lb, h3);
  sage2_mm<<<8192, 64, 0, stream>>>(h3, s2lw, s2rw, hl2, hr2);
  sage2_final<<<8192, 64, 0, stream>>>(hl2, hr2, offs, csr, inv, s2lb, out);
}

// Round 11
// 1871.245 us; speedup vs baseline: 1.4186x; 1.0621x over previous
//
#include <hip/hip_runtime.h>

// ---------------------------------------------------------------------------
// SAGENET: x:(8192,16384)f32 -> lin1(16384->4096,relu) -> lin2(4096->2048,relu)
// -> SAGEConv(2048->1024,relu) -> SAGEConv(1024->10,relu) -> softmax
// R11: R8's proven GEMM (256x256, BK=64, dbuf 128 KiB, 0-conflict swizzle,
//      one __syncthreads/K-tile, XCD-partitioned mapping) + A_F32 variant for
//      gemm1: f32 A loaded to regs at loop top (pre-swizzled source), cvt to
//      bf16 and ds_write'd into the SAME linear LDS bytes after the MFMA
//      phase (T14 issue-early/write-late). Deletes the 130 µs cvt-x kernel
//      and ~512 MiB of HBM traffic. Identical LDS bytes -> absmax canary
//      0.002929688 must hold exactly.
//      Schedule verdict (R4/R6/R7/R9/R10 all failed): 2-barrier BK=64 is the
//      ceiling for this structure family (~959 TF); do not re-attack.
// Workspace peak: ~505.2 MiB (xb region now unused; hlr1 reuses ws+0).
// ---------------------------------------------------------------------------

typedef short  short8   __attribute__((ext_vector_type(8)));
typedef float  floatx4  __attribute__((ext_vector_type(4)));
typedef unsigned short ushort8v __attribute__((ext_vector_type(8)));
typedef unsigned short ushort4v __attribute__((ext_vector_type(4)));
typedef unsigned short ushort;

__device__ __forceinline__ ushort f2bf(float f) {
  unsigned u = __float_as_uint(f);
  u += 0x7fffu + ((u >> 16) & 1u);   // round-to-nearest-even
  return (ushort)(u >> 16);
}
__device__ __forceinline__ float bf2f(ushort h) {
  return __uint_as_float(((unsigned)h) << 16);
}

__device__ __forceinline__ void gload16(const void* g, void* l) {
  __builtin_amdgcn_global_load_lds(
      (const __attribute__((address_space(1))) void*)g,
      (__attribute__((address_space(3))) void*)l, 16, 0, 0);
}

// ---------------- f32 -> bf16 conversion (vectorized, grid-stride) ----------
__global__ __launch_bounds__(256) void cvt_f32_bf16(
    const float* __restrict__ in, ushort* __restrict__ out, long n8) {
  long i = (long)blockIdx.x * blockDim.x + threadIdx.x;
  const long stride = (long)gridDim.x * blockDim.x;
  for (; i < n8; i += stride) {
    const float4* p = (const float4*)(in + i * 8);
    float4 a = p[0], b = p[1];
    ushort8v o;
    o[0] = f2bf(a.x); o[1] = f2bf(a.y); o[2] = f2bf(a.z); o[3] = f2bf(a.w);
    o[4] = f2bf(b.x); o[5] = f2bf(b.y); o[6] = f2bf(b.z); o[7] = f2bf(b.w);
    *(ushort8v*)(out + i * 8) = o;
  }
}

// ---------------- CSR build -------------------------------------------------
__global__ void edge_count(const int* __restrict__ dst, int E, int* __restrict__ deg) {
  int e = blockIdx.x * 256 + threadIdx.x;
  if (e < E) atomicAdd(&deg[dst[e]], 1);
}

__global__ __launch_bounds__(256) void scan_k(
    const int* __restrict__ deg, int* __restrict__ offs, float* __restrict__ inv, int n) {
  __shared__ int part[256];
  const int t = threadIdx.x;
  int local[32];
  int s = 0;
  const int base = t * 32;
#pragma unroll
  for (int i = 0; i < 32; ++i) { local[i] = s; s += deg[base + i]; }
  part[t] = s;
  __syncthreads();
  for (int off = 1; off < 256; off <<= 1) {
    int v = (t >= off) ? part[t - off] : 0;
    __syncthreads();
    part[t] += v;
    __syncthreads();
  }
  const int prev = (t == 0) ? 0 : part[t - 1];
  if (t == 255) offs[n] = part[255];
#pragma unroll
  for (int i = 0; i < 32; ++i) {
    const int e = base + i;
    offs[e] = prev + local[i];
    const int d = deg[e];
    inv[e] = (d > 0) ? (1.0f / (float)d) : 0.0f;
  }
}

__global__ void edge_fill(const int* __restrict__ src, const int* __restrict__ dst, int E,
                          const int* __restrict__ offs, int* __restrict__ fill,
                          int* __restrict__ csr) {
  int e = blockIdx.x * 256 + threadIdx.x;
  if (e < E) {
    const int d = dst[e];
    const int p = offs[d] + atomicAdd(&fill[d], 1);
    csr[p] = src[e];
  }
}

// ---------------- bf16 GEMM 256x256, C = A * B^T ----------------------------
// A: [M,K] row-major (bf16, or f32 when A_F32 via Af); B: [N,K] bf16.
// BK=64, 8 waves (2Mx4N), per-wave 128x64 (acc[8][4]), dbuf 128 KiB LDS.
// LDS: 256 rows x 128 B/tile; logical (row, col16) at byte
// row*128 + ((col16 ^ (row&7))<<4)  -> 0 bank conflicts (R3/R5/R8-measured).
// bf16 A/B staged via global_load_lds with pre-swizzled SOURCE, linear dest.
// f32 A (A_F32): same chunk mapping, loaded to regs at loop top, cvt+stored
// to the same linear LDS bytes after MFMA phase (identical bytes -> identical
// results). Block mapping: XCD x (= blockIdx%8) owns bm panels, bn inner.
template <int A_F32, int OUT_BF16, int RELU, int HAS_BIAS>
__global__ __launch_bounds__(512, 2) void gemm256(
    const float* __restrict__ Af, const ushort* __restrict__ A,
    const ushort* __restrict__ Bm,
    const float* __restrict__ bias, void* __restrict__ Cout,
    int M, int N, int K) {
  extern __shared__ char smem[];   // 131072 B: buf0{A,B}, buf1{A,B} each 32 KiB

  const int nbn = N >> 8;
  const int nbm8 = (M >> 8) >> 3;        // bm panels per XCD
  const int x = blockIdx.x & 7;          // XCD id under round-robin dispatch
  const int j = blockIdx.x >> 3;
  const int bm = x * nbm8 + j / nbn;
  const int bn = j % nbn;

  const int t = threadIdx.x;
  const int w = t >> 6, lane = t & 63;
  const int wr = w >> 2, wc = w & 3;

  // ---- staging addresses (source pre-swizzled; row = t>>3, chunk cswz) ----
  const int cswz = (t & 7) ^ ((t >> 3) & 7);
  const ushort* Ag  = A_F32 ? nullptr
                            : A + (size_t)(bm * 256 + (t >> 3)) * K + cswz * 8;
  const float*  Axg = A_F32 ? Af + (size_t)(bm * 256 + (t >> 3)) * K + cswz * 8
                            : nullptr;
  const ushort* Bg = Bm + (size_t)(bn * 256 + (t >> 3)) * K + cswz * 8;
  const int stOff = w * 1024;            // wave base; lane*16 added by HW/DS

  // ---- fragment read addresses (swizzled) ----
  const int rA = wr * 128 + (lane & 15);
  const int rB = wc * 64 + (lane & 15);
  const int s0 = (((lane >> 4) ^ (lane & 7)) << 4);  // kh=0 slot byte offset

  floatx4 acc[8][4] = {};
  const int NT = K >> 6;

  // prologue: stage K-tile 0 into buffer 0
  if (A_F32) {
    float4 ar[8];
#pragma unroll
    for (int i = 0; i < 4; ++i) {
      ar[2 * i]     = *(const float4*)(Axg + (size_t)(i * 64) * K);
      ar[2 * i + 1] = *(const float4*)(Axg + (size_t)(i * 64) * K + 4);
    }
    char* lb = smem + 32768 + stOff;
#pragma unroll
    for (int i = 0; i < 4; ++i) gload16(Bg + (size_t)(i * 64) * K, lb + i * 8192);
#pragma unroll
    for (int i = 0; i < 4; ++i) {
      const float4 u = ar[2 * i], v = ar[2 * i + 1];
      ushort8v o;
      o[0] = f2bf(u.x); o[1] = f2bf(u.y); o[2] = f2bf(u.z); o[3] = f2bf(u.w);
      o[4] = f2bf(v.x); o[5] = f2bf(v.y); o[6] = f2bf(v.z); o[7] = f2bf(v.w);
      *(ushort8v*)(smem + i * 8192 + t * 16) = o;
    }
  } else {
    char* la = smem + stOff;
    char* lb = la + 32768;
#pragma unroll
    for (int i = 0; i < 4; ++i) gload16(Ag + (size_t)(i * 64) * K, la + i * 8192);
#pragma unroll
    for (int i = 0; i < 4; ++i) gload16(Bg + (size_t)(i * 64) * K, lb + i * 8192);
  }
  __syncthreads();

  for (int kt = 0; kt < NT; ++kt) {
    const bool hasNext = (kt + 1 < NT);
    float4 ar[8];

    // issue next tile's loads first (issue-early)
    if (hasNext) {
      const int k0 = (kt + 1) << 6;
      if (A_F32) {
#pragma unroll
        for (int i = 0; i < 4; ++i) {
          ar[2 * i]     = *(const float4*)(Axg + (size_t)(i * 64) * K + k0);
          ar[2 * i + 1] = *(const float4*)(Axg + (size_t)(i * 64) * K + k0 + 4);
        }
      } else {
        char* la = smem + ((kt + 1) & 1) * 65536 + stOff;
#pragma unroll
        for (int i = 0; i < 4; ++i) gload16(Ag + (size_t)(i * 64) * K + k0, la + i * 8192);
      }
      char* lb = smem + ((kt + 1) & 1) * 65536 + 32768 + stOff;
#pragma unroll
      for (int i = 0; i < 4; ++i) gload16(Bg + (size_t)(i * 64) * K + k0, lb + i * 8192);
    }

    const char* pa = smem + (kt & 1) * 65536 + rA * 128;
    const char* pb = smem + (kt & 1) * 65536 + 32768 + rB * 128;

    // kh=0 fragments + MFMAs
    short8 a0[8], b0[4];
#pragma unroll
    for (int mi = 0; mi < 8; ++mi) a0[mi] = *(const short8*)(pa + mi * 2048 + s0);
#pragma unroll
    for (int ni = 0; ni < 4; ++ni) b0[ni] = *(const short8*)(pb + ni * 2048 + s0);
#pragma unroll
    for (int mi = 0; mi < 8; ++mi)
#pragma unroll
      for (int ni = 0; ni < 4; ++ni)
        acc[mi][ni] = __builtin_amdgcn_mfma_f32_16x16x32_bf16(a0[mi], b0[ni], acc[mi][ni], 0, 0, 0);

    // kh=1 fragments + MFMAs
    short8 a1[8], b1[4];
#pragma unroll
    for (int mi = 0; mi < 8; ++mi) a1[mi] = *(const short8*)(pa + mi * 2048 + (s0 ^ 64));
#pragma unroll
    for (int ni = 0; ni < 4; ++ni) b1[ni] = *(const short8*)(pb + ni * 2048 + (s0 ^ 64));
#pragma unroll
    for (int mi = 0; mi < 8; ++mi)
#pragma unroll
      for (int ni = 0; ni < 4; ++ni)
        acc[mi][ni] = __builtin_amdgcn_mfma_f32_16x16x32_bf16(a1[mi], b1[ni], acc[mi][ni], 0, 0, 0);

    // write-late: cvt + LDS store for the f32 A tile (same bytes gload wrote)
    if (hasNext && A_F32) {
      char* la = smem + ((kt + 1) & 1) * 65536;
#pragma unroll
      for (int i = 0; i < 4; ++i) {
        const float4 u = ar[2 * i], v = ar[2 * i + 1];
        ushort8v o;
        o[0] = f2bf(u.x); o[1] = f2bf(u.y); o[2] = f2bf(u.z); o[3] = f2bf(u.w);
        o[4] = f2bf(v.x); o[5] = f2bf(v.y); o[6] = f2bf(v.z); o[7] = f2bf(v.w);
        *(ushort8v*)(la + i * 8192 + t * 16) = o;
      }
    }

    __syncthreads();  // drains staging; next buffer fully ready
  }

  // epilogue: C/D layout col=lane&15, row=(lane>>4)*4+j (m89-verified)
  const int row0 = bm * 256 + wr * 128 + ((lane >> 4) << 2);
  const int col0 = bn * 256 + wc * 64 + (lane & 15);
#pragma unroll
  for (int ni = 0; ni < 4; ++ni) {
    const int col = col0 + ni * 16;
    const float bv = HAS_BIAS ? bias[col] : 0.0f;
#pragma unroll
    for (int mi = 0; mi < 8; ++mi) {
#pragma unroll
      for (int j2 = 0; j2 < 4; ++j2) {
        const int row = row0 + mi * 16 + j2;
        float v = acc[mi][ni][j2] + bv;
        if (RELU) v = fmaxf(v, 0.0f);
        if (OUT_BF16)
          ((ushort*)Cout)[(size_t)row * N + col] = f2bf(v);
        else
          ((float*)Cout)[(size_t)row * N + col] = v;
      }
    }
  }
}

// ---------------- SAGE1 aggregation + combine (bf16 hlr1) -------------------
__global__ __launch_bounds__(256) void sage1_agg(
    const ushort* __restrict__ hlr1, const int* __restrict__ offs,
    const int* __restrict__ csr, const float* __restrict__ inv,
    const float* __restrict__ lb, ushort* __restrict__ h3) {
  const int dn = blockIdx.x;
  const int f4 = threadIdx.x * 4;
  float ax = 0.f, ay = 0.f, az = 0.f, aw = 0.f;
  const int e0 = offs[dn], e1 = offs[dn + 1];
  for (int e = e0; e < e1; ++e) {
    const int s = csr[e];
    const ushort4v v = *(const ushort4v*)(hlr1 + (size_t)s * 2048 + f4);
    ax += bf2f(v[0]); ay += bf2f(v[1]); az += bf2f(v[2]); aw += bf2f(v[3]);
  }
  const float iv = inv[dn];
  const ushort4v hr = *(const ushort4v*)(hlr1 + (size_t)dn * 2048 + 1024 + f4);
  const float4 bb = *(const float4*)(lb + f4);
  ushort4v o;
  o[0] = f2bf(fmaxf(ax * iv + bb.x + bf2f(hr[0]), 0.0f));
  o[1] = f2bf(fmaxf(ay * iv + bb.y + bf2f(hr[1]), 0.0f));
  o[2] = f2bf(fmaxf(az * iv + bb.z + bf2f(hr[2]), 0.0f));
  o[3] = f2bf(fmaxf(aw * iv + bb.w + bf2f(hr[3]), 0.0f));
  *(ushort4v*)(h3 + (size_t)dn * 1024 + f4) = o;
}

// ---------------- SAGE2 projections (K=1024, N=10 each) ---------------------
__global__ __launch_bounds__(64) void sage2_mm(
    const ushort* __restrict__ h3, const float* __restrict__ wl,
    const float* __restrict__ wr, float* __restrict__ hl2, float* __restrict__ hr2) {
  const int row = blockIdx.x;
  const int l = threadIdx.x;
  float hv[16];
  {
    ushort8v p0 = *(const ushort8v*)(h3 + (size_t)row * 1024 + l * 16);
    ushort8v p1 = *(const ushort8v*)(h3 + (size_t)row * 1024 + l * 16 + 8);
#pragma unroll
    for (int i = 0; i < 8; ++i) { hv[i] = bf2f(p0[i]); hv[8 + i] = bf2f(p1[i]); }
  }
  float al[10] = {}, ar[10] = {};
#pragma unroll
  for (int i = 0; i < 16; ++i) {
    const int k = l * 16 + i;
    const float h = hv[i];
#pragma unroll
    for (int j = 0; j < 10; ++j) {
      al[j] = fmaf(h, wl[j * 1024 + k], al[j]);
      ar[j] = fmaf(h, wr[j * 1024 + k], ar[j]);
    }
  }
#pragma unroll
  for (int j = 0; j < 10; ++j) {
#pragma unroll
    for (int off = 32; off > 0; off >>= 1) {
      al[j] += __shfl_down(al[j], off);
      ar[j] += __shfl_down(ar[j], off);
    }
  }
  if (l == 0) {
#pragma unroll
    for (int j = 0; j < 10; ++j) {
      hl2[(size_t)row * 10 + j] = al[j];
      hr2[(size_t)row * 10 + j] = ar[j];
    }
  }
}

// ---------------- SAGE2 aggregation + combine + softmax ---------------------
__global__ __launch_bounds__(64) void sage2_final(
    const float* __restrict__ hl2, const float* __restrict__ hr2,
    const int* __restrict__ offs, const int* __restrict__ csr,
    const float* __restrict__ inv, const float* __restrict__ lb,
    float* __restrict__ out) {
  const int dn = blockIdx.x;
  const int l = threadIdx.x;
  float a[10] = {};
  const int e0 = offs[dn], e1 = offs[dn + 1];
  for (int e = e0 + l; e < e1; e += 64) {
    const int s = csr[e];
#pragma unroll
    for (int j = 0; j < 10; ++j) a[j] += hl2[(size_t)s * 10 + j];
  }
#pragma unroll
  for (int j = 0; j < 10; ++j)
#pragma unroll
    for (int off = 32; off > 0; off >>= 1) a[j] += __shfl_down(a[j], off);
  if (l == 0) {
    const float iv = inv[dn];
    float v[10];
    float m = -1e30f;
#pragma unroll
    for (int j = 0; j < 10; ++j) {
      v[j] = fmaxf(a[j] * iv + lb[j] + hr2[(size_t)dn * 10 + j], 0.0f);
      m = fmaxf(m, v[j]);
    }
    float ssum = 0.0f;
#pragma unroll
    for (int j = 0; j < 10; ++j) { v[j] = __expf(v[j] - m); ssum += v[j]; }
    const float r = 1.0f / ssum;
#pragma unroll
    for (int j = 0; j < 10; ++j) out[(size_t)dn * 10 + j] = v[j] * r;
  }
}

// ---------------------------------------------------------------------------
extern "C" void kernel_launch(void* const* d_in, const int* in_sizes, int n_in,
                              void* d_out, int out_size, void* d_ws, size_t ws_size,
                              hipStream_t stream) {
  const float* x    = (const float*)d_in[0];
  const int*   ei   = (const int*)d_in[1];
  const float* w1   = (const float*)d_in[2];
  const float* b1   = (const float*)d_in[3];
  const float* w2   = (const float*)d_in[4];
  const float* b2   = (const float*)d_in[5];
  const float* s1lw = (const float*)d_in[6];
  const float* s1lb = (const float*)d_in[7];
  const float* s1rw = (const float*)d_in[8];
  const float* s2lw = (const float*)d_in[9];
  const float* s2lb = (const float*)d_in[10];
  const float* s2rw = (const float*)d_in[11];
  float* out = (float*)d_out;
  char* ws = (char*)d_ws;

  const int E = in_sizes[1] / 2;  // 262144
  const int Nn = 8192;

  // allow 128 KiB dynamic LDS for the GEMM instantiations (idempotent)
  hipFuncSetAttribute((const void*)&gemm256<1, 1, 1, 1>,
                      hipFuncAttributeMaxDynamicSharedMemorySize, 131072);
  hipFuncSetAttribute((const void*)&gemm256<0, 1, 1, 1>,
                      hipFuncAttributeMaxDynamicSharedMemorySize, 131072);
  hipFuncSetAttribute((const void*)&gemm256<0, 1, 0, 0>,
                      hipFuncAttributeMaxDynamicSharedMemorySize, 131072);

  // ---- workspace layout (bytes) ----
  ushort* w1b = (ushort*)(ws + 268435456L);   // 128 MiB
  ushort* h1  = (ushort*)(ws + 402653184L);   //  64 MiB
  ushort* w2b = (ushort*)(ws + 469762048L);   //  16 MiB
  ushort* h2  = (ushort*)(ws + 486539264L);   //  32 MiB
  ushort* ws1 = (ushort*)(ws + 520093696L);   //   8 MiB  [s1_l_w ; s1_r_w]
  char* csrb = ws + 528482304L;
  int*   deg  = (int*)(csrb);
  int*   fill = (int*)(csrb + 32768);
  int*   offs = (int*)(csrb + 65536);
  float* inv  = (float*)(csrb + 98816);
  int*   csr  = (int*)(csrb + 131584);
  // region reuse (ws+0 free: gemm1 reads x directly now):
  ushort* hlr1 = (ushort*)(ws + 0L);                // 32 MiB bf16 [hl1 | hr1]
  ushort* h3   = (ushort*)(ws + 67108864L);         // 16 MiB
  float*  hl2  = (float*)(ws + 83886080L);
  float*  hr2  = (float*)(ws + 84213760L);

  const int* esrc = ei;
  const int* edst = ei + E;

  hipMemsetAsync(deg, 0, 65536, stream);  // deg + fill counters

  // bf16 conversions (x conversion now fused into gemm1)
  cvt_f32_bf16<<<2048, 256, 0, stream>>>(w1, w1b, 8388608L);
  cvt_f32_bf16<<<1024, 256, 0, stream>>>(w2, w2b, 1048576L);
  cvt_f32_bf16<<<256, 256, 0, stream>>>(s1lw, ws1, 262144L);
  cvt_f32_bf16<<<256, 256, 0, stream>>>(s1rw, ws1 + 2097152L, 262144L);

  // CSR build
  edge_count<<<(E + 255) / 256, 256, 0, stream>>>(edst, E, deg);
  scan_k<<<1, 256, 0, stream>>>(deg, offs, inv, Nn);
  edge_fill<<<(E + 255) / 256, 256, 0, stream>>>(esrc, edst, E, offs, fill, csr);

  // MLP (256x256-tile GEMMs, 128 KiB dynamic LDS)
  gemm256<1, 1, 1, 1><<<512, 512, 131072, stream>>>(x, nullptr, w1b, b1, h1, 8192, 4096, 16384);
  gemm256<0, 1, 1, 1><<<256, 512, 131072, stream>>>(nullptr, h1, w2b, b2, h2, 8192, 2048, 4096);
  // fused SAGE1 projections: [hl1 | hr1] = h2 @ [s1_l_w ; s1_r_w]^T  (bf16 out)
  gemm256<0, 1, 0, 0><<<256, 512, 131072, stream>>>(nullptr, h2, ws1, nullptr, hlr1, 8192, 2048, 2048);

  sage1_agg<<<8192, 256, 0, stream>>>(hlr1, offs, csr, inv, s1lb, h3);
  sage2_mm<<<8192, 64, 0, stream>>>(h3, s2lw, s2rw, hl2, hr2);
  sage2_final<<<8192, 64, 0, stream>>>(hl2, hr2, offs, csr, inv, s2lb, out);
}

// Round 12
// 1672.555 us; speedup vs baseline: 1.5871x; 1.1188x over previous
//
#include <hip/hip_runtime.h>

// ---------------------------------------------------------------------------
// SAGENET: x:(8192,16384)f32 -> lin1(16384->4096,relu) -> lin2(4096->2048,relu)
// -> SAGEConv(2048->1024,relu) -> SAGEConv(1024->10,relu) -> softmax
// R12: GEMM reverted to R8 exactly (256x256, BK=64, dbuf 128 KiB LDS,
//      global_load_lds staging w/ pre-swizzled source, 0-conflict swizzle,
//      one __syncthreads/K-tile, XCD-partitioned mapping, launch_bounds(512,2)).
//      Verdicts now locked from 6 experiments:
//        - schedule family pinned at ~959 TF (R4/R6/R7/R9/R10 all regressed)
//        - gload_lds-direct staging is load-bearing (R11 reg-staging -25%)
//      New: sage2_mm v2 — 512 blocks x 256 thr, 16 rows/block, weights in
//      LDS (80 KiB), staggered float4 walk (2-way banks = free; r-groups
//      broadcast), shfl reduction. ~640 MiB L2 re-reads -> 40 MiB.
// Workspace peak: ~505.2 MiB.
// ---------------------------------------------------------------------------

typedef short  short8   __attribute__((ext_vector_type(8)));
typedef float  floatx4  __attribute__((ext_vector_type(4)));
typedef unsigned short ushort8v __attribute__((ext_vector_type(8)));
typedef unsigned short ushort4v __attribute__((ext_vector_type(4)));
typedef unsigned short ushort;

__device__ __forceinline__ ushort f2bf(float f) {
  unsigned u = __float_as_uint(f);
  u += 0x7fffu + ((u >> 16) & 1u);   // round-to-nearest-even
  return (ushort)(u >> 16);
}
__device__ __forceinline__ float bf2f(ushort h) {
  return __uint_as_float(((unsigned)h) << 16);
}

__device__ __forceinline__ void gload16(const void* g, void* l) {
  __builtin_amdgcn_global_load_lds(
      (const __attribute__((address_space(1))) void*)g,
      (__attribute__((address_space(3))) void*)l, 16, 0, 0);
}

// ---------------- f32 -> bf16 conversion (vectorized, grid-stride) ----------
__global__ __launch_bounds__(256) void cvt_f32_bf16(
    const float* __restrict__ in, ushort* __restrict__ out, long n8) {
  long i = (long)blockIdx.x * blockDim.x + threadIdx.x;
  const long stride = (long)gridDim.x * blockDim.x;
  for (; i < n8; i += stride) {
    const float4* p = (const float4*)(in + i * 8);
    float4 a = p[0], b = p[1];
    ushort8v o;
    o[0] = f2bf(a.x); o[1] = f2bf(a.y); o[2] = f2bf(a.z); o[3] = f2bf(a.w);
    o[4] = f2bf(b.x); o[5] = f2bf(b.y); o[6] = f2bf(b.z); o[7] = f2bf(b.w);
    *(ushort8v*)(out + i * 8) = o;
  }
}

// ---------------- CSR build -------------------------------------------------
__global__ void edge_count(const int* __restrict__ dst, int E, int* __restrict__ deg) {
  int e = blockIdx.x * 256 + threadIdx.x;
  if (e < E) atomicAdd(&deg[dst[e]], 1);
}

__global__ __launch_bounds__(256) void scan_k(
    const int* __restrict__ deg, int* __restrict__ offs, float* __restrict__ inv, int n) {
  __shared__ int part[256];
  const int t = threadIdx.x;
  int local[32];
  int s = 0;
  const int base = t * 32;
#pragma unroll
  for (int i = 0; i < 32; ++i) { local[i] = s; s += deg[base + i]; }
  part[t] = s;
  __syncthreads();
  for (int off = 1; off < 256; off <<= 1) {
    int v = (t >= off) ? part[t - off] : 0;
    __syncthreads();
    part[t] += v;
    __syncthreads();
  }
  const int prev = (t == 0) ? 0 : part[t - 1];
  if (t == 255) offs[n] = part[255];
#pragma unroll
  for (int i = 0; i < 32; ++i) {
    const int e = base + i;
    offs[e] = prev + local[i];
    const int d = deg[e];
    inv[e] = (d > 0) ? (1.0f / (float)d) : 0.0f;
  }
}

__global__ void edge_fill(const int* __restrict__ src, const int* __restrict__ dst, int E,
                          const int* __restrict__ offs, int* __restrict__ fill,
                          int* __restrict__ csr) {
  int e = blockIdx.x * 256 + threadIdx.x;
  if (e < E) {
    const int d = dst[e];
    const int p = offs[d] + atomicAdd(&fill[d], 1);
    csr[p] = src[e];
  }
}

// ---------------- bf16 GEMM 256x256, C = A * B^T (R8, proven) ---------------
// A: [M,K] bf16 row-major; B: [N,K] bf16 row-major. BK=64, 8 waves (2Mx4N),
// per-wave 128x64 output (acc[8][4]), double-buffered 128 KiB LDS.
// LDS: 256 rows x 128 B/tile; logical (row, col16) at byte
// row*128 + ((col16 ^ (row&7))<<4)  -> 0 bank conflicts (R3/R5/R8-measured).
// global_load_lds keeps linear LDS dest; SOURCE pre-permuted by the same
// involution. Block mapping: XCD x (= blockIdx%8) owns bm panels, bn inner.
template <int OUT_BF16, int RELU, int HAS_BIAS>
__global__ __launch_bounds__(512, 2) void gemm256(
    const ushort* __restrict__ A, const ushort* __restrict__ Bm,
    const float* __restrict__ bias, void* __restrict__ Cout,
    int M, int N, int K) {
  extern __shared__ char smem[];   // 131072 B: buf0{A,B}, buf1{A,B} each 32 KiB

  const int nbn = N >> 8;
  const int nbm8 = (M >> 8) >> 3;        // bm panels per XCD
  const int x = blockIdx.x & 7;          // XCD id under round-robin dispatch
  const int j = blockIdx.x >> 3;
  const int bm = x * nbm8 + j / nbn;
  const int bn = j % nbn;

  const int t = threadIdx.x;
  const int w = t >> 6, lane = t & 63;
  const int wr = w >> 2, wc = w & 3;

  // ---- staging addresses (source pre-swizzled) ----
  const int cswz = (t & 7) ^ ((t >> 3) & 7);
  const ushort* Ag = A  + (size_t)(bm * 256 + (t >> 3)) * K + cswz * 8;
  const ushort* Bg = Bm + (size_t)(bn * 256 + (t >> 3)) * K + cswz * 8;
  const int stOff = w * 1024;

  // ---- fragment read addresses (swizzled) ----
  const int rA = wr * 128 + (lane & 15);
  const int rB = wc * 64 + (lane & 15);
  const int s0 = (((lane >> 4) ^ (lane & 7)) << 4);  // kh=0 slot byte offset

  floatx4 acc[8][4] = {};
  const int NT = K >> 6;

  // prologue: stage K-tile 0 into buffer 0
  {
    char* la = smem + stOff;
    char* lb = la + 32768;
#pragma unroll
    for (int i = 0; i < 4; ++i) gload16(Ag + (size_t)(i * 64) * K, la + i * 8192);
#pragma unroll
    for (int i = 0; i < 4; ++i) gload16(Bg + (size_t)(i * 64) * K, lb + i * 8192);
  }
  __syncthreads();

  for (int kt = 0; kt < NT; ++kt) {
    const char* pa = smem + (kt & 1) * 65536 + rA * 128;
    const char* pb = smem + (kt & 1) * 65536 + 32768 + rB * 128;

    // kh=0 fragments
    short8 a0[8], b0[4];
#pragma unroll
    for (int mi = 0; mi < 8; ++mi) a0[mi] = *(const short8*)(pa + mi * 2048 + s0);
#pragma unroll
    for (int ni = 0; ni < 4; ++ni) b0[ni] = *(const short8*)(pb + ni * 2048 + s0);

    // prefetch next K-tile into the other buffer (hidden under MFMA phase)
    if (kt + 1 < NT) {
      const int k0 = (kt + 1) << 6;
      char* la = smem + ((kt + 1) & 1) * 65536 + stOff;
      char* lb = la + 32768;
#pragma unroll
      for (int i = 0; i < 4; ++i) gload16(Ag + (size_t)(i * 64) * K + k0, la + i * 8192);
#pragma unroll
      for (int i = 0; i < 4; ++i) gload16(Bg + (size_t)(i * 64) * K + k0, lb + i * 8192);
    }

#pragma unroll
    for (int mi = 0; mi < 8; ++mi)
#pragma unroll
      for (int ni = 0; ni < 4; ++ni)
        acc[mi][ni] = __builtin_amdgcn_mfma_f32_16x16x32_bf16(a0[mi], b0[ni], acc[mi][ni], 0, 0, 0);

    // kh=1 fragments
    short8 a1[8], b1[4];
#pragma unroll
    for (int mi = 0; mi < 8; ++mi) a1[mi] = *(const short8*)(pa + mi * 2048 + (s0 ^ 64));
#pragma unroll
    for (int ni = 0; ni < 4; ++ni) b1[ni] = *(const short8*)(pb + ni * 2048 + (s0 ^ 64));

#pragma unroll
    for (int mi = 0; mi < 8; ++mi)
#pragma unroll
      for (int ni = 0; ni < 4; ++ni)
        acc[mi][ni] = __builtin_amdgcn_mfma_f32_16x16x32_bf16(a1[mi], b1[ni], acc[mi][ni], 0, 0, 0);

    __syncthreads();  // vmcnt(0)+lgkmcnt(0)+barrier: next buffer fully staged
  }

  // epilogue: C/D layout col=lane&15, row=(lane>>4)*4+j (m89-verified)
  const int row0 = bm * 256 + wr * 128 + ((lane >> 4) << 2);
  const int col0 = bn * 256 + wc * 64 + (lane & 15);
#pragma unroll
  for (int ni = 0; ni < 4; ++ni) {
    const int col = col0 + ni * 16;
    const float bv = HAS_BIAS ? bias[col] : 0.0f;
#pragma unroll
    for (int mi = 0; mi < 8; ++mi) {
#pragma unroll
      for (int j2 = 0; j2 < 4; ++j2) {
        const int row = row0 + mi * 16 + j2;
        float v = acc[mi][ni][j2] + bv;
        if (RELU) v = fmaxf(v, 0.0f);
        if (OUT_BF16)
          ((ushort*)Cout)[(size_t)row * N + col] = f2bf(v);
        else
          ((float*)Cout)[(size_t)row * N + col] = v;
      }
    }
  }
}

// ---------------- SAGE1 aggregation + combine (bf16 hlr1) -------------------
__global__ __launch_bounds__(256) void sage1_agg(
    const ushort* __restrict__ hlr1, const int* __restrict__ offs,
    const int* __restrict__ csr, const float* __restrict__ inv,
    const float* __restrict__ lb, ushort* __restrict__ h3) {
  const int dn = blockIdx.x;
  const int f4 = threadIdx.x * 4;
  float ax = 0.f, ay = 0.f, az = 0.f, aw = 0.f;
  const int e0 = offs[dn], e1 = offs[dn + 1];
  for (int e = e0; e < e1; ++e) {
    const int s = csr[e];
    const ushort4v v = *(const ushort4v*)(hlr1 + (size_t)s * 2048 + f4);
    ax += bf2f(v[0]); ay += bf2f(v[1]); az += bf2f(v[2]); aw += bf2f(v[3]);
  }
  const float iv = inv[dn];
  const ushort4v hr = *(const ushort4v*)(hlr1 + (size_t)dn * 2048 + 1024 + f4);
  const float4 bb = *(const float4*)(lb + f4);
  ushort4v o;
  o[0] = f2bf(fmaxf(ax * iv + bb.x + bf2f(hr[0]), 0.0f));
  o[1] = f2bf(fmaxf(ay * iv + bb.y + bf2f(hr[1]), 0.0f));
  o[2] = f2bf(fmaxf(az * iv + bb.z + bf2f(hr[2]), 0.0f));
  o[3] = f2bf(fmaxf(aw * iv + bb.w + bf2f(hr[3]), 0.0f));
  *(ushort4v*)(h3 + (size_t)dn * 1024 + f4) = o;
}

// ---------------- SAGE2 projections v2 (weights in LDS, 16 rows/block) ------
// hl2/hr2[row][j] = sum_k h3[row][k] * w{l,r}[j][k],  j<10, k<1024.
// 512 blocks x 256 thr. Thread t: row r = t>>4, k-slice c = t&15 (64 elems).
// Weights staged in LDS once (80 KiB). Staggered float4 walk f=(ii+c)&15:
// 16 c-lanes cover banks 2-way (free, m136); the 4 r-groups read the same
// addresses (broadcast). Row-reduce over c via __shfl_down (within 16 lanes).
__global__ __launch_bounds__(256) void sage2_mm(
    const ushort* __restrict__ h3, const float* __restrict__ wl,
    const float* __restrict__ wr, float* __restrict__ hl2, float* __restrict__ hr2) {
  __shared__ float wds[20480];   // [0..10239]=wl, [10240..20479]=wr
  const int t = threadIdx.x;
  // stage weights: 5120 float4 over 256 threads = 20 each
  for (int i = t; i < 2560; i += 256)
    *(float4*)&wds[i * 4] = *(const float4*)&wl[i * 4];
  for (int i = t; i < 2560; i += 256)
    *(float4*)&wds[10240 + i * 4] = *(const float4*)&wr[i * 4];
  __syncthreads();

  const int r = t >> 4, c = t & 15;
  const int row = blockIdx.x * 16 + r;

  // load this thread's 64-element h3 slice
  float hv[64];
#pragma unroll
  for (int ii = 0; ii < 8; ++ii) {
    ushort8v p = *(const ushort8v*)(h3 + (size_t)row * 1024 + c * 64 + ii * 8);
#pragma unroll
    for (int k = 0; k < 8; ++k) hv[ii * 8 + k] = bf2f(p[k]);
  }

  float al[10] = {}, ar[10] = {};
#pragma unroll
  for (int j = 0; j < 10; ++j) {
    const int base = j * 1024 + c * 64;
#pragma unroll
    for (int ii = 0; ii < 16; ++ii) {
      const int f = (ii + c) & 15;    // staggered float4 index
      const float4 lv = *(const float4*)&wds[base + f * 4];
      const float4 rv = *(const float4*)&wds[10240 + base + f * 4];
      const float h0 = hv[f * 4], h1 = hv[f * 4 + 1],
                  h2 = hv[f * 4 + 2], h3v = hv[f * 4 + 3];
      al[j] = fmaf(h0, lv.x, fmaf(h1, lv.y, fmaf(h2, lv.z, fmaf(h3v, lv.w, al[j]))));
      ar[j] = fmaf(h0, rv.x, fmaf(h1, rv.y, fmaf(h2, rv.z, fmaf(h3v, rv.w, ar[j]))));
    }
  }
#pragma unroll
  for (int j = 0; j < 10; ++j) {
#pragma unroll
    for (int off = 8; off > 0; off >>= 1) {
      al[j] += __shfl_down(al[j], off);
      ar[j] += __shfl_down(ar[j], off);
    }
  }
  if (c == 0) {
#pragma unroll
    for (int j = 0; j < 10; ++j) {
      hl2[(size_t)row * 10 + j] = al[j];
      hr2[(size_t)row * 10 + j] = ar[j];
    }
  }
}

// ---------------- SAGE2 aggregation + combine + softmax ---------------------
__global__ __launch_bounds__(64) void sage2_final(
    const float* __restrict__ hl2, const float* __restrict__ hr2,
    const int* __restrict__ offs, const int* __restrict__ csr,
    const float* __restrict__ inv, const float* __restrict__ lb,
    float* __restrict__ out) {
  const int dn = blockIdx.x;
  const int l = threadIdx.x;
  float a[10] = {};
  const int e0 = offs[dn], e1 = offs[dn + 1];
  for (int e = e0 + l; e < e1; e += 64) {
    const int s = csr[e];
#pragma unroll
    for (int j = 0; j < 10; ++j) a[j] += hl2[(size_t)s * 10 + j];
  }
#pragma unroll
  for (int j = 0; j < 10; ++j)
#pragma unroll
    for (int off = 32; off > 0; off >>= 1) a[j] += __shfl_down(a[j], off);
  if (l == 0) {
    const float iv = inv[dn];
    float v[10];
    float m = -1e30f;
#pragma unroll
    for (int j = 0; j < 10; ++j) {
      v[j] = fmaxf(a[j] * iv + lb[j] + hr2[(size_t)dn * 10 + j], 0.0f);
      m = fmaxf(m, v[j]);
    }
    float ssum = 0.0f;
#pragma unroll
    for (int j = 0; j < 10; ++j) { v[j] = __expf(v[j] - m); ssum += v[j]; }
    const float r = 1.0f / ssum;
#pragma unroll
    for (int j = 0; j < 10; ++j) out[(size_t)dn * 10 + j] = v[j] * r;
  }
}

// ---------------------------------------------------------------------------
extern "C" void kernel_launch(void* const* d_in, const int* in_sizes, int n_in,
                              void* d_out, int out_size, void* d_ws, size_t ws_size,
                              hipStream_t stream) {
  const float* x    = (const float*)d_in[0];
  const int*   ei   = (const int*)d_in[1];
  const float* w1   = (const float*)d_in[2];
  const float* b1   = (const float*)d_in[3];
  const float* w2   = (const float*)d_in[4];
  const float* b2   = (const float*)d_in[5];
  const float* s1lw = (const float*)d_in[6];
  const float* s1lb = (const float*)d_in[7];
  const float* s1rw = (const float*)d_in[8];
  const float* s2lw = (const float*)d_in[9];
  const float* s2lb = (const float*)d_in[10];
  const float* s2rw = (const float*)d_in[11];
  float* out = (float*)d_out;
  char* ws = (char*)d_ws;

  const int E = in_sizes[1] / 2;  // 262144
  const int Nn = 8192;

  // allow 128 KiB dynamic LDS for the GEMM instantiations (idempotent)
  hipFuncSetAttribute((const void*)&gemm256<1, 1, 1>,
                      hipFuncAttributeMaxDynamicSharedMemorySize, 131072);
  hipFuncSetAttribute((const void*)&gemm256<1, 0, 0>,
                      hipFuncAttributeMaxDynamicSharedMemorySize, 131072);

  // ---- workspace layout (bytes) ----
  ushort* xb  = (ushort*)(ws + 0L);           // 256 MiB
  ushort* w1b = (ushort*)(ws + 268435456L);   // 128 MiB
  ushort* h1  = (ushort*)(ws + 402653184L);   //  64 MiB
  ushort* w2b = (ushort*)(ws + 469762048L);   //  16 MiB
  ushort* h2  = (ushort*)(ws + 486539264L);   //  32 MiB
  ushort* ws1 = (ushort*)(ws + 520093696L);   //   8 MiB  [s1_l_w ; s1_r_w]
  char* csrb = ws + 528482304L;
  int*   deg  = (int*)(csrb);
  int*   fill = (int*)(csrb + 32768);
  int*   offs = (int*)(csrb + 65536);
  float* inv  = (float*)(csrb + 98816);
  int*   csr  = (int*)(csrb + 131584);
  // region reuse (xb dead after GEMM1, h1 dead after GEMM2):
  ushort* hlr1 = (ushort*)(ws + 0L);                // 32 MiB bf16 [hl1 | hr1]
  ushort* h3   = (ushort*)(ws + 67108864L);         // 16 MiB
  float*  hl2  = (float*)(ws + 83886080L);
  float*  hr2  = (float*)(ws + 84213760L);

  const int* esrc = ei;
  const int* edst = ei + E;

  hipMemsetAsync(deg, 0, 65536, stream);  // deg + fill counters

  // bf16 conversions
  cvt_f32_bf16<<<4096, 256, 0, stream>>>(x, xb, 16777216L);
  cvt_f32_bf16<<<2048, 256, 0, stream>>>(w1, w1b, 8388608L);
  cvt_f32_bf16<<<1024, 256, 0, stream>>>(w2, w2b, 1048576L);
  cvt_f32_bf16<<<256, 256, 0, stream>>>(s1lw, ws1, 262144L);
  cvt_f32_bf16<<<256, 256, 0, stream>>>(s1rw, ws1 + 2097152L, 262144L);

  // CSR build
  edge_count<<<(E + 255) / 256, 256, 0, stream>>>(edst, E, deg);
  scan_k<<<1, 256, 0, stream>>>(deg, offs, inv, Nn);
  edge_fill<<<(E + 255) / 256, 256, 0, stream>>>(esrc, edst, E, offs, fill, csr);

  // MLP (256x256-tile GEMMs, 128 KiB dynamic LDS)
  gemm256<1, 1, 1><<<512, 512, 131072, stream>>>(xb, w1b, b1, h1, 8192, 4096, 16384);
  gemm256<1, 1, 1><<<256, 512, 131072, stream>>>(h1, w2b, b2, h2, 8192, 2048, 4096);
  // fused SAGE1 projections: [hl1 | hr1] = h2 @ [s1_l_w ; s1_r_w]^T  (bf16 out)
  gemm256<1, 0, 0><<<256, 512, 131072, stream>>>(h2, ws1, nullptr, hlr1, 8192, 2048, 2048);

  sage1_agg<<<8192, 256, 0, stream>>>(hlr1, offs, csr, inv, s1lb, h3);
  sage2_mm<<<512, 256, 0, stream>>>(h3, s2lw, s2rw, hl2, hr2);
  sage2_final<<<8192, 64, 0, stream>>>(hl2, hr2, offs, csr, inv, s2lb, out);
}

// Round 13
// 1364.755 us; speedup vs baseline: 1.9451x; 1.2255x over previous
//
#include <hip/hip_runtime.h>

// ---------------------------------------------------------------------------
// SAGENET: x:(8192,16384)f32 -> lin1(16384->4096,relu) -> lin2(4096->2048,relu)
// -> SAGEConv(2048->1024,relu) -> SAGEConv(1024->10,relu) -> softmax
// R13: faithful m201-style 8-phase GEMM on R12's proven geometry.
//      Tile 256x256, BK=64, 8 waves (2Mx4N), acc[8][4], dbuf 128 KiB LDS,
//      SAME layout/swizzle/addressing as R12 (0 conflicts measured).
//      Loop re-phased: 8 phases per 2 K-tiles; phase = C-quadrant (2mi x 4ni
//      x K64, 16 MFMA); B frags read once per tile (ph1/ph5), held in regs;
//      one half-tile stage per phase; vmcnt(4) only at ph4/ph8 (never 0);
//      ONE s_barrier per phase. Stage targets one phase after last reader:
//        ph1: A(buf1,t1) both halves   [A buf1 freed at prev ph8 barrier]
//        ph2/ph3: B(buf0,t2) h0/h1     [B buf0 last read ph1]
//        ph5/ph6: A(buf0,t2) h0/h1     [A buf0 last read ph4]
//        ph7/ph8: B(buf1,t3) h0/h1     [B buf1 last read ph5]
//      Read-set and stage-set disjoint within every phase -> race-free.
//      Per-fragment MFMA order identical to R12 -> absmax canary 0.002929688.
// Workspace peak: ~505.2 MiB.
// ---------------------------------------------------------------------------

typedef short  short8   __attribute__((ext_vector_type(8)));
typedef float  floatx4  __attribute__((ext_vector_type(4)));
typedef unsigned short ushort8v __attribute__((ext_vector_type(8)));
typedef unsigned short ushort4v __attribute__((ext_vector_type(4)));
typedef unsigned short ushort;

__device__ __forceinline__ ushort f2bf(float f) {
  unsigned u = __float_as_uint(f);
  u += 0x7fffu + ((u >> 16) & 1u);   // round-to-nearest-even
  return (ushort)(u >> 16);
}
__device__ __forceinline__ float bf2f(ushort h) {
  return __uint_as_float(((unsigned)h) << 16);
}

__device__ __forceinline__ void gload16(const void* g, void* l) {
  __builtin_amdgcn_global_load_lds(
      (const __attribute__((address_space(1))) void*)g,
      (__attribute__((address_space(3))) void*)l, 16, 0, 0);
}

// ---------------- f32 -> bf16 conversion (vectorized, grid-stride) ----------
__global__ __launch_bounds__(256) void cvt_f32_bf16(
    const float* __restrict__ in, ushort* __restrict__ out, long n8) {
  long i = (long)blockIdx.x * blockDim.x + threadIdx.x;
  const long stride = (long)gridDim.x * blockDim.x;
  for (; i < n8; i += stride) {
    const float4* p = (const float4*)(in + i * 8);
    float4 a = p[0], b = p[1];
    ushort8v o;
    o[0] = f2bf(a.x); o[1] = f2bf(a.y); o[2] = f2bf(a.z); o[3] = f2bf(a.w);
    o[4] = f2bf(b.x); o[5] = f2bf(b.y); o[6] = f2bf(b.z); o[7] = f2bf(b.w);
    *(ushort8v*)(out + i * 8) = o;
  }
}

// ---------------- CSR build -------------------------------------------------
__global__ void edge_count(const int* __restrict__ dst, int E, int* __restrict__ deg) {
  int e = blockIdx.x * 256 + threadIdx.x;
  if (e < E) atomicAdd(&deg[dst[e]], 1);
}

__global__ __launch_bounds__(256) void scan_k(
    const int* __restrict__ deg, int* __restrict__ offs, float* __restrict__ inv, int n) {
  __shared__ int part[256];
  const int t = threadIdx.x;
  int local[32];
  int s = 0;
  const int base = t * 32;
#pragma unroll
  for (int i = 0; i < 32; ++i) { local[i] = s; s += deg[base + i]; }
  part[t] = s;
  __syncthreads();
  for (int off = 1; off < 256; off <<= 1) {
    int v = (t >= off) ? part[t - off] : 0;
    __syncthreads();
    part[t] += v;
    __syncthreads();
  }
  const int prev = (t == 0) ? 0 : part[t - 1];
  if (t == 255) offs[n] = part[255];
#pragma unroll
  for (int i = 0; i < 32; ++i) {
    const int e = base + i;
    offs[e] = prev + local[i];
    const int d = deg[e];
    inv[e] = (d > 0) ? (1.0f / (float)d) : 0.0f;
  }
}

__global__ void edge_fill(const int* __restrict__ src, const int* __restrict__ dst, int E,
                          const int* __restrict__ offs, int* __restrict__ fill,
                          int* __restrict__ csr) {
  int e = blockIdx.x * 256 + threadIdx.x;
  if (e < E) {
    const int d = dst[e];
    const int p = offs[d] + atomicAdd(&fill[d], 1);
    csr[p] = src[e];
  }
}

// ---------------- bf16 GEMM 256x256, C = A * B^T, 8-phase (m201-style) ------
template <int OUT_BF16, int RELU, int HAS_BIAS>
__global__ __launch_bounds__(512, 2) void gemm256(
    const ushort* __restrict__ A, const ushort* __restrict__ Bm,
    const float* __restrict__ bias, void* __restrict__ Cout,
    int M, int N, int K) {
  extern __shared__ char smem[];   // buf d at d*65536: A 32 KiB | B 32 KiB

  const int nbn = N >> 8;
  const int nbm8 = (M >> 8) >> 3;        // bm panels per XCD
  const int x = blockIdx.x & 7;          // XCD id under round-robin dispatch
  const int j = blockIdx.x >> 3;
  const int bm = x * nbm8 + j / nbn;
  const int bn = j % nbn;

  const int t = threadIdx.x;
  const int w = t >> 6, lane = t & 63;
  const int wr = w >> 2, wc = w & 3;

  // ---- staging addresses (source pre-swizzled; identical to R12) ----
  const int cswz = (t & 7) ^ ((t >> 3) & 7);
  const ushort* Ag = A  + (size_t)(bm * 256 + (t >> 3)) * K + cswz * 8;
  const ushort* Bg = Bm + (size_t)(bn * 256 + (t >> 3)) * K + cswz * 8;
  const int stOff = w * 1024;

  // ---- fragment read addresses (identical to R12) ----
  const int rA = wr * 128 + (lane & 15);
  const int rB = wc * 64 + (lane & 15);
  const int s0 = (((lane >> 4) ^ (lane & 7)) << 4);

  floatx4 acc[8][4] = {};
  const int NT = K >> 6;        // K-tiles (even for all our K)
  const int NIT = NT >> 1;      // iterations (2 tiles each)

  // stage one M-half (h) of A or B for K-tile kt into buffer buf
#define STGA(BUF, KT, H)                                                      \
  {                                                                           \
    const int k0_ = (((KT) < NT) ? (KT) : 0) << 6;                            \
    char* la_ = smem + (BUF) * 65536 + stOff;                                 \
    gload16(Ag + (size_t)(((H) * 2) * 64) * K + k0_, la_ + ((H) * 2) * 8192); \
    gload16(Ag + (size_t)(((H) * 2 + 1) * 64) * K + k0_,                      \
            la_ + ((H) * 2 + 1) * 8192);                                      \
  }
#define STGB(BUF, KT, H)                                                      \
  {                                                                           \
    const int k0_ = (((KT) < NT) ? (KT) : 0) << 6;                            \
    char* lb_ = smem + (BUF) * 65536 + 32768 + stOff;                         \
    gload16(Bg + (size_t)(((H) * 2) * 64) * K + k0_, lb_ + ((H) * 2) * 8192); \
    gload16(Bg + (size_t)(((H) * 2 + 1) * 64) * K + k0_,                      \
            lb_ + ((H) * 2 + 1) * 8192);                                      \
  }

  // phase: read A-quadrant Q (2 mi) [+ B frags if READB], stage (__VA_ARGS__),
  // optional vmcnt(4), one barrier, 16 MFMA under setprio.
#define PH(BUF, Q, READB, DOWAIT, ...)                                        \
  {                                                                           \
    const char* pa_ = smem + (BUF) * 65536 + rA * 128;                        \
    short8 a00 = *(const short8*)(pa_ + (2 * (Q)) * 2048 + s0);               \
    short8 a01 = *(const short8*)(pa_ + (2 * (Q)) * 2048 + (s0 ^ 64));        \
    short8 a10 = *(const short8*)(pa_ + (2 * (Q) + 1) * 2048 + s0);           \
    short8 a11 = *(const short8*)(pa_ + (2 * (Q) + 1) * 2048 + (s0 ^ 64));    \
    if (READB) {                                                              \
      const char* pb_ = smem + (BUF) * 65536 + 32768 + rB * 128;              \
      _Pragma("unroll") for (int ni = 0; ni < 4; ++ni) {                      \
        bfv0[ni] = *(const short8*)(pb_ + ni * 2048 + s0);                    \
        bfv1[ni] = *(const short8*)(pb_ + ni * 2048 + (s0 ^ 64));             \
      }                                                                       \
    }                                                                         \
    __VA_ARGS__;                                                              \
    if (DOWAIT) asm volatile("s_waitcnt vmcnt(4)" ::: "memory");              \
    __builtin_amdgcn_s_barrier();                                             \
    __builtin_amdgcn_s_setprio(1);                                            \
    _Pragma("unroll") for (int ni = 0; ni < 4; ++ni) {                        \
      acc[2 * (Q)][ni] = __builtin_amdgcn_mfma_f32_16x16x32_bf16(             \
          a00, bfv0[ni], acc[2 * (Q)][ni], 0, 0, 0);                          \
      acc[2 * (Q) + 1][ni] = __builtin_amdgcn_mfma_f32_16x16x32_bf16(         \
          a10, bfv0[ni], acc[2 * (Q) + 1][ni], 0, 0, 0);                      \
    }                                                                         \
    _Pragma("unroll") for (int ni = 0; ni < 4; ++ni) {                        \
      acc[2 * (Q)][ni] = __builtin_amdgcn_mfma_f32_16x16x32_bf16(             \
          a01, bfv1[ni], acc[2 * (Q)][ni], 0, 0, 0);                          \
      acc[2 * (Q) + 1][ni] = __builtin_amdgcn_mfma_f32_16x16x32_bf16(         \
          a11, bfv1[ni], acc[2 * (Q) + 1][ni], 0, 0, 0);                      \
    }                                                                         \
    __builtin_amdgcn_s_setprio(0);                                            \
    asm volatile("" ::: "memory");                                            \
  }

  // prologue: A(t0), B(t0), B(t1) = 12 loads; land tile0's 8, leave B(t1)=4
  STGA(0, 0, 0); STGA(0, 0, 1);
  STGB(0, 0, 0); STGB(0, 0, 1);
  STGB(1, 1, 0); STGB(1, 1, 1);
  asm volatile("s_waitcnt vmcnt(4)" ::: "memory");
  __builtin_amdgcn_s_barrier();
  asm volatile("" ::: "memory");

  for (int it = 0; it < NIT; ++it) {
    const int t1 = 2 * it + 1, t2 = 2 * it + 2, t3 = 2 * it + 3;
    short8 bfv0[4], bfv1[4];
    PH(0, 0, 1, 0, STGA(1, t1, 0); STGA(1, t1, 1));   // ph1
    PH(0, 1, 0, 0, STGB(0, t2, 0));                   // ph2
    PH(0, 2, 0, 0, STGB(0, t2, 1));                   // ph3
    PH(0, 3, 0, 1, );                                 // ph4: vmcnt(4)
    PH(1, 0, 1, 0, STGA(0, t2, 0));                   // ph5
    PH(1, 1, 0, 0, STGA(0, t2, 1));                   // ph6
    PH(1, 2, 0, 0, STGB(1, t3, 0));                   // ph7
    PH(1, 3, 0, 1, STGB(1, t3, 1));                   // ph8: vmcnt(4)
  }
  asm volatile("s_waitcnt vmcnt(0)" ::: "memory");    // drain tail stages

#undef STGA
#undef STGB
#undef PH

  // epilogue: C/D layout col=lane&15, row=(lane>>4)*4+j (m89-verified)
  const int row0 = bm * 256 + wr * 128 + ((lane >> 4) << 2);
  const int col0 = bn * 256 + wc * 64 + (lane & 15);
#pragma unroll
  for (int ni = 0; ni < 4; ++ni) {
    const int col = col0 + ni * 16;
    const float bv = HAS_BIAS ? bias[col] : 0.0f;
#pragma unroll
    for (int mi = 0; mi < 8; ++mi) {
#pragma unroll
      for (int j2 = 0; j2 < 4; ++j2) {
        const int row = row0 + mi * 16 + j2;
        float v = acc[mi][ni][j2] + bv;
        if (RELU) v = fmaxf(v, 0.0f);
        if (OUT_BF16)
          ((ushort*)Cout)[(size_t)row * N + col] = f2bf(v);
        else
          ((float*)Cout)[(size_t)row * N + col] = v;
      }
    }
  }
}

// ---------------- SAGE1 aggregation + combine (bf16 hlr1) -------------------
__global__ __launch_bounds__(256) void sage1_agg(
    const ushort* __restrict__ hlr1, const int* __restrict__ offs,
    const int* __restrict__ csr, const float* __restrict__ inv,
    const float* __restrict__ lb, ushort* __restrict__ h3) {
  const int dn = blockIdx.x;
  const int f4 = threadIdx.x * 4;
  float ax = 0.f, ay = 0.f, az = 0.f, aw = 0.f;
  const int e0 = offs[dn], e1 = offs[dn + 1];
  for (int e = e0; e < e1; ++e) {
    const int s = csr[e];
    const ushort4v v = *(const ushort4v*)(hlr1 + (size_t)s * 2048 + f4);
    ax += bf2f(v[0]); ay += bf2f(v[1]); az += bf2f(v[2]); aw += bf2f(v[3]);
  }
  const float iv = inv[dn];
  const ushort4v hr = *(const ushort4v*)(hlr1 + (size_t)dn * 2048 + 1024 + f4);
  const float4 bb = *(const float4*)(lb + f4);
  ushort4v o;
  o[0] = f2bf(fmaxf(ax * iv + bb.x + bf2f(hr[0]), 0.0f));
  o[1] = f2bf(fmaxf(ay * iv + bb.y + bf2f(hr[1]), 0.0f));
  o[2] = f2bf(fmaxf(az * iv + bb.z + bf2f(hr[2]), 0.0f));
  o[3] = f2bf(fmaxf(aw * iv + bb.w + bf2f(hr[3]), 0.0f));
  *(ushort4v*)(h3 + (size_t)dn * 1024 + f4) = o;
}

// ---------------- SAGE2 projections v2 (weights in LDS, 16 rows/block) ------
__global__ __launch_bounds__(256) void sage2_mm(
    const ushort* __restrict__ h3, const float* __restrict__ wl,
    const float* __restrict__ wr, float* __restrict__ hl2, float* __restrict__ hr2) {
  __shared__ float wds[20480];   // [0..10239]=wl, [10240..20479]=wr
  const int t = threadIdx.x;
  for (int i = t; i < 2560; i += 256)
    *(float4*)&wds[i * 4] = *(const float4*)&wl[i * 4];
  for (int i = t; i < 2560; i += 256)
    *(float4*)&wds[10240 + i * 4] = *(const float4*)&wr[i * 4];
  __syncthreads();

  const int r = t >> 4, c = t & 15;
  const int row = blockIdx.x * 16 + r;

  float hv[64];
#pragma unroll
  for (int ii = 0; ii < 8; ++ii) {
    ushort8v p = *(const ushort8v*)(h3 + (size_t)row * 1024 + c * 64 + ii * 8);
#pragma unroll
    for (int k = 0; k < 8; ++k) hv[ii * 8 + k] = bf2f(p[k]);
  }

  float al[10] = {}, ar[10] = {};
#pragma unroll
  for (int j = 0; j < 10; ++j) {
    const int base = j * 1024 + c * 64;
#pragma unroll
    for (int ii = 0; ii < 16; ++ii) {
      const int f = (ii + c) & 15;    // staggered float4 index
      const float4 lv = *(const float4*)&wds[base + f * 4];
      const float4 rv = *(const float4*)&wds[10240 + base + f * 4];
      const float h0 = hv[f * 4], h1 = hv[f * 4 + 1],
                  h2 = hv[f * 4 + 2], h3v = hv[f * 4 + 3];
      al[j] = fmaf(h0, lv.x, fmaf(h1, lv.y, fmaf(h2, lv.z, fmaf(h3v, lv.w, al[j]))));
      ar[j] = fmaf(h0, rv.x, fmaf(h1, rv.y, fmaf(h2, rv.z, fmaf(h3v, rv.w, ar[j]))));
    }
  }
#pragma unroll
  for (int j = 0; j < 10; ++j) {
#pragma unroll
    for (int off = 8; off > 0; off >>= 1) {
      al[j] += __shfl_down(al[j], off);
      ar[j] += __shfl_down(ar[j], off);
    }
  }
  if (c == 0) {
#pragma unroll
    for (int j = 0; j < 10; ++j) {
      hl2[(size_t)row * 10 + j] = al[j];
      hr2[(size_t)row * 10 + j] = ar[j];
    }
  }
}

// ---------------- SAGE2 aggregation + combine + softmax ---------------------
__global__ __launch_bounds__(64) void sage2_final(
    const float* __restrict__ hl2, const float* __restrict__ hr2,
    const int* __restrict__ offs, const int* __restrict__ csr,
    const float* __restrict__ inv, const float* __restrict__ lb,
    float* __restrict__ out) {
  const int dn = blockIdx.x;
  const int l = threadIdx.x;
  float a[10] = {};
  const int e0 = offs[dn], e1 = offs[dn + 1];
  for (int e = e0 + l; e < e1; e += 64) {
    const int s = csr[e];
#pragma unroll
    for (int j = 0; j < 10; ++j) a[j] += hl2[(size_t)s * 10 + j];
  }
#pragma unroll
  for (int j = 0; j < 10; ++j)
#pragma unroll
    for (int off = 32; off > 0; off >>= 1) a[j] += __shfl_down(a[j], off);
  if (l == 0) {
    const float iv = inv[dn];
    float v[10];
    float m = -1e30f;
#pragma unroll
    for (int j = 0; j < 10; ++j) {
      v[j] = fmaxf(a[j] * iv + lb[j] + hr2[(size_t)dn * 10 + j], 0.0f);
      m = fmaxf(m, v[j]);
    }
    float ssum = 0.0f;
#pragma unroll
    for (int j = 0; j < 10; ++j) { v[j] = __expf(v[j] - m); ssum += v[j]; }
    const float r = 1.0f / ssum;
#pragma unroll
    for (int j = 0; j < 10; ++j) out[(size_t)dn * 10 + j] = v[j] * r;
  }
}

// ---------------------------------------------------------------------------
extern "C" void kernel_launch(void* const* d_in, const int* in_sizes, int n_in,
                              void* d_out, int out_size, void* d_ws, size_t ws_size,
                              hipStream_t stream) {
  const float* x    = (const float*)d_in[0];
  const int*   ei   = (const int*)d_in[1];
  const float* w1   = (const float*)d_in[2];
  const float* b1   = (const float*)d_in[3];
  const float* w2   = (const float*)d_in[4];
  const float* b2   = (const float*)d_in[5];
  const float* s1lw = (const float*)d_in[6];
  const float* s1lb = (const float*)d_in[7];
  const float* s1rw = (const float*)d_in[8];
  const float* s2lw = (const float*)d_in[9];
  const float* s2lb = (const float*)d_in[10];
  const float* s2rw = (const float*)d_in[11];
  float* out = (float*)d_out;
  char* ws = (char*)d_ws;

  const int E = in_sizes[1] / 2;  // 262144
  const int Nn = 8192;

  // allow 128 KiB dynamic LDS for the GEMM instantiations (idempotent)
  hipFuncSetAttribute((const void*)&gemm256<1, 1, 1>,
                      hipFuncAttributeMaxDynamicSharedMemorySize, 131072);
  hipFuncSetAttribute((const void*)&gemm256<1, 0, 0>,
                      hipFuncAttributeMaxDynamicSharedMemorySize, 131072);

  // ---- workspace layout (bytes) ----
  ushort* xb  = (ushort*)(ws + 0L);           // 256 MiB
  ushort* w1b = (ushort*)(ws + 268435456L);   // 128 MiB
  ushort* h1  = (ushort*)(ws + 402653184L);   //  64 MiB
  ushort* w2b = (ushort*)(ws + 469762048L);   //  16 MiB
  ushort* h2  = (ushort*)(ws + 486539264L);   //  32 MiB
  ushort* ws1 = (ushort*)(ws + 520093696L);   //   8 MiB  [s1_l_w ; s1_r_w]
  char* csrb = ws + 528482304L;
  int*   deg  = (int*)(csrb);
  int*   fill = (int*)(csrb + 32768);
  int*   offs = (int*)(csrb + 65536);
  float* inv  = (float*)(csrb + 98816);
  int*   csr  = (int*)(csrb + 131584);
  // region reuse (xb dead after GEMM1, h1 dead after GEMM2):
  ushort* hlr1 = (ushort*)(ws + 0L);                // 32 MiB bf16 [hl1 | hr1]
  ushort* h3   = (ushort*)(ws + 67108864L);         // 16 MiB
  float*  hl2  = (float*)(ws + 83886080L);
  float*  hr2  = (float*)(ws + 84213760L);

  const int* esrc = ei;
  const int* edst = ei + E;

  hipMemsetAsync(deg, 0, 65536, stream);  // deg + fill counters

  // bf16 conversions
  cvt_f32_bf16<<<4096, 256, 0, stream>>>(x, xb, 16777216L);
  cvt_f32_bf16<<<2048, 256, 0, stream>>>(w1, w1b, 8388608L);
  cvt_f32_bf16<<<1024, 256, 0, stream>>>(w2, w2b, 1048576L);
  cvt_f32_bf16<<<256, 256, 0, stream>>>(s1lw, ws1, 262144L);
  cvt_f32_bf16<<<256, 256, 0, stream>>>(s1rw, ws1 + 2097152L, 262144L);

  // CSR build
  edge_count<<<(E + 255) / 256, 256, 0, stream>>>(edst, E, deg);
  scan_k<<<1, 256, 0, stream>>>(deg, offs, inv, Nn);
  edge_fill<<<(E + 255) / 256, 256, 0, stream>>>(esrc, edst, E, offs, fill, csr);

  // MLP (256x256-tile GEMMs, 128 KiB dynamic LDS, 8-phase pipeline)
  gemm256<1, 1, 1><<<512, 512, 131072, stream>>>(xb, w1b, b1, h1, 8192, 4096, 16384);
  gemm256<1, 1, 1><<<256, 512, 131072, stream>>>(h1, w2b, b2, h2, 8192, 2048, 4096);
  // fused SAGE1 projections: [hl1 | hr1] = h2 @ [s1_l_w ; s1_r_w]^T  (bf16 out)
  gemm256<1, 0, 0><<<256, 512, 131072, stream>>>(h2, ws1, nullptr, hlr1, 8192, 2048, 2048);

  sage1_agg<<<8192, 256, 0, stream>>>(hlr1, offs, csr, inv, s1lb, h3);
  sage2_mm<<<512, 256, 0, stream>>>(h3, s2lw, s2rw, hl2, hr2);
  sage2_final<<<8192, 64, 0, stream>>>(hl2, hr2, offs, csr, inv, s2lb, out);
}